// Round 13
// baseline (589.325 us; speedup 1.0000x reference)
//
#include <hip/hip_runtime.h>
#include <hip/hip_bf16.h>
#include <cstdint>

#define BS     2048   // B*S tokens
#define DMODEL 1024
#define RANK   512
#define NEXP   32
#define DSP    64
#define NHEAD  16
#define DHEAD  64
#define SEQ    1024
#define BATCH  2
#define HALL_N 384    // 6*DSP
#define WSTR   ((size_t)BS * NEXP)
#define LSTR   ((size_t)NEXP * BS)

typedef unsigned short u16;
typedef unsigned int u32;
typedef __attribute__((ext_vector_type(8))) short short8;
typedef __attribute__((ext_vector_type(4))) float f32x4;

__device__ __forceinline__ u16 bfbits(float x) {
  __hip_bfloat16 h = __float2bfloat16(x);
  return __builtin_bit_cast(u16, h);
}
__device__ __forceinline__ float b2f(u16 u) {
  unsigned int x = (unsigned int)u << 16;
  return __builtin_bit_cast(float, x);
}

// ---------------- LayerNorm (token per block, 256 thr, float4), fp32 + bf16 out ----
__global__ void ln_kernel(const float* __restrict__ x,
                          const float* __restrict__ sc,
                          const float* __restrict__ bi,
                          float* __restrict__ out,
                          u16* __restrict__ outb) {
  int tok = blockIdx.x;
  int t = threadIdx.x; // 256
  const float4* xr = reinterpret_cast<const float4*>(x + (size_t)tok * DMODEL);
  float4 v = xr[t];
  float s = v.x + v.y + v.z + v.w;
  float q = v.x * v.x + v.y * v.y + v.z * v.z + v.w * v.w;
#pragma unroll
  for (int off = 32; off > 0; off >>= 1) {
    s += __shfl_xor(s, off);
    q += __shfl_xor(q, off);
  }
  __shared__ float red[8];
  int wid = t >> 6;
  if ((t & 63) == 0) { red[wid] = s; red[4 + wid] = q; }
  __syncthreads();
  s = red[0] + red[1] + red[2] + red[3];
  q = red[4] + red[5] + red[6] + red[7];
  float mu = s * (1.f / DMODEL);
  float var = q * (1.f / DMODEL) - mu * mu;
  float inv = rsqrtf(var + 1e-6f);
  float4 scv = reinterpret_cast<const float4*>(sc)[t];
  float4 biv = reinterpret_cast<const float4*>(bi)[t];
  float4 r;
  r.x = (v.x - mu) * inv * scv.x + biv.x;
  r.y = (v.y - mu) * inv * scv.y + biv.y;
  r.z = (v.z - mu) * inv * scv.z + biv.z;
  r.w = (v.w - mu) * inv * scv.w + biv.w;
  reinterpret_cast<float4*>(out + (size_t)tok * DMODEL)[t] = r;
  ushort4 ob;
  ob.x = bfbits(r.x); ob.y = bfbits(r.y); ob.z = bfbits(r.z); ob.w = bfbits(r.w);
  reinterpret_cast<ushort4*>(outb + (size_t)tok * DMODEL)[t] = ob;
}

// ---------------- emb row L2-normalize ----------------
__global__ void embnorm_kernel(const float* __restrict__ e, float* __restrict__ o) {
  int row = blockIdx.x;
  int lane = threadIdx.x; // 64
  float v = e[row * DSP + lane];
  float q = v * v;
#pragma unroll
  for (int off = 32; off > 0; off >>= 1) q += __shfl_xor(q, off);
  o[row * DSP + lane] = v / (sqrtf(q) + 1e-8f);
}

// ---------------- fp32 split-K GEMM: part[ks] = A[M,Kc]@B[Kc,N] ----------------
__global__ __launch_bounds__(256) void gemm_splitk(const float* __restrict__ A,
                                                   const float* __restrict__ Bm,
                                                   float* __restrict__ part,
                                                   int M, int N, int K, int kchunk) {
  __shared__ float As[16][65];
  __shared__ float Bs[16][64];
  int n0 = blockIdx.x * 64;
  int m0 = blockIdx.y * 64;
  int kbeg = blockIdx.z * kchunk;
  int t = threadIdx.x;
  int tx = t & 15, ty = t >> 4;
  float c[4][4] = {};
  for (int k0 = kbeg; k0 < kbeg + kchunk; k0 += 16) {
#pragma unroll
    for (int i = 0; i < 4; i++) {
      int idx = t + i * 256;
      int m = idx >> 4, kk = idx & 15;
      As[kk][m] = A[(size_t)(m0 + m) * K + k0 + kk];
    }
#pragma unroll
    for (int i = 0; i < 4; i++) {
      int idx = t + i * 256;
      int kk = idx >> 6, nn = idx & 63;
      Bs[kk][nn] = Bm[(size_t)(k0 + kk) * N + n0 + nn];
    }
    __syncthreads();
#pragma unroll
    for (int kk = 0; kk < 16; kk++) {
      float a[4], b[4];
#pragma unroll
      for (int i = 0; i < 4; i++) a[i] = As[kk][ty + i * 16];
#pragma unroll
      for (int j = 0; j < 4; j++) b[j] = Bs[kk][tx + j * 16];
#pragma unroll
      for (int i = 0; i < 4; i++)
#pragma unroll
        for (int j = 0; j < 4; j++) c[i][j] += a[i] * b[j];
    }
    __syncthreads();
  }
  float* po = part + (size_t)blockIdx.z * M * N;
#pragma unroll
  for (int i = 0; i < 4; i++)
#pragma unroll
    for (int j = 0; j < 4; j++)
      po[(size_t)(m0 + ty + i * 16) * N + n0 + tx + j * 16] = c[i][j];
}

// ---------------- batched split-K for W_fk+W_rk (z = wsel*8 + ks) ----------------
__global__ __launch_bounds__(256) void gemm_splitk2(const float* __restrict__ A,
                                                    const float* __restrict__ B0,
                                                    const float* __restrict__ B1,
                                                    float* __restrict__ part,
                                                    int M, int N, int K, int kchunk) {
  __shared__ float As[16][65];
  __shared__ float Bs[16][64];
  int wsel = blockIdx.z >> 3, ks = blockIdx.z & 7;
  const float* Bm = wsel ? B1 : B0;
  int n0 = blockIdx.x * 64;
  int m0 = blockIdx.y * 64;
  int kbeg = ks * kchunk;
  int t = threadIdx.x;
  int tx = t & 15, ty = t >> 4;
  float c[4][4] = {};
  for (int k0 = kbeg; k0 < kbeg + kchunk; k0 += 16) {
#pragma unroll
    for (int i = 0; i < 4; i++) {
      int idx = t + i * 256;
      int m = idx >> 4, kk = idx & 15;
      As[kk][m] = A[(size_t)(m0 + m) * K + k0 + kk];
    }
#pragma unroll
    for (int i = 0; i < 4; i++) {
      int idx = t + i * 256;
      int kk = idx >> 6, nn = idx & 63;
      Bs[kk][nn] = Bm[(size_t)(k0 + kk) * N + n0 + nn];
    }
    __syncthreads();
#pragma unroll
    for (int kk = 0; kk < 16; kk++) {
      float a[4], b[4];
#pragma unroll
      for (int i = 0; i < 4; i++) a[i] = As[kk][ty + i * 16];
#pragma unroll
      for (int j = 0; j < 4; j++) b[j] = Bs[kk][tx + j * 16];
#pragma unroll
      for (int i = 0; i < 4; i++)
#pragma unroll
        for (int j = 0; j < 4; j++) c[i][j] += a[i] * b[j];
    }
    __syncthreads();
  }
  float* po = part + (size_t)blockIdx.z * M * N;
#pragma unroll
  for (int i = 0; i < 4; i++)
#pragma unroll
    for (int j = 0; j < 4; j++)
      po[(size_t)(m0 + ty + i * 16) * N + n0 + tx + j * 16] = c[i][j];
}

// ---------------- split-K reduce + bias ----------------
__global__ void reduce_bias_kernel(const float* __restrict__ part,
                                   const float* __restrict__ bias,
                                   float* __restrict__ out,
                                   int MN, int N, int KS) {
  int i = blockIdx.x * 256 + threadIdx.x;
  if (i * 4 >= MN) return;
  float4 s = reinterpret_cast<const float4*>(part)[i];
  for (int ks = 1; ks < KS; ks++) {
    float4 p = reinterpret_cast<const float4*>(part + (size_t)ks * MN)[i];
    s.x += p.x; s.y += p.y; s.z += p.z; s.w += p.w;
  }
  int col = (i * 4) % N;
  float4 b = *reinterpret_cast<const float4*>(bias + col);
  s.x += b.x; s.y += b.y; s.z += b.z; s.w += b.w;
  reinterpret_cast<float4*>(out)[i] = s;
}

// ---------------- batched reduce for W_fk/W_rk (blockIdx.y = wsel) ----------------
__global__ void reduce_bias2_kernel(const float* __restrict__ part,
                                    const float* __restrict__ bias0,
                                    const float* __restrict__ bias1,
                                    float* __restrict__ out,
                                    int MN, int N, int KS) {
  int wsel = blockIdx.y;
  const float* p0 = part + (size_t)wsel * KS * MN;
  const float* bias = wsel ? bias1 : bias0;
  float* o = out + (size_t)wsel * MN;
  int i = blockIdx.x * 256 + threadIdx.x;
  if (i * 4 >= MN) return;
  float4 s = reinterpret_cast<const float4*>(p0)[i];
  for (int ks = 1; ks < KS; ks++) {
    float4 p = reinterpret_cast<const float4*>(p0 + (size_t)ks * MN)[i];
    s.x += p.x; s.y += p.y; s.z += p.z; s.w += p.w;
  }
  int col = (i * 4) % N;
  float4 b = *reinterpret_cast<const float4*>(bias + col);
  s.x += b.x; s.y += b.y; s.z += b.z; s.w += b.w;
  reinterpret_cast<float4*>(o)[i] = s;
}

// ------- batched routing: blockIdx.y = r, global route = R0 + r -------
__global__ void route_kernel(const float* __restrict__ h, size_t roff, int ldh,
                             const float* __restrict__ embn, int R0,
                             float* __restrict__ w8) {
  int tok = blockIdx.x;
  int r = blockIdx.y;
  int gr = R0 + r;
  int pool = (gr < 2) ? 0 : (gr < 3) ? 1 : (gr < 5) ? 2 : (gr < 6) ? 3 : (gr < 7) ? 4 : 5;
  const float* e = embn + (size_t)pool * NEXP * DSP;
  const float* hr = h + (size_t)r * roff;
  float* wout = w8 + (size_t)gr * WSTR;
  int lane = threadIdx.x; // 64
  __shared__ float hs[DSP];
  __shared__ float es[NEXP * DSP];
  hs[lane] = hr[(size_t)tok * ldh + lane];
#pragma unroll
  for (int i = 0; i < NEXP * DSP / 64; i++) es[lane + i * 64] = e[lane + i * 64];
  __syncthreads();
  float logit = -1e30f;
  if (lane < NEXP) {
    float s = 0.f;
#pragma unroll
    for (int d = 0; d < DSP; d++) s += hs[d] * es[lane * DSP + d];
    logit = s;
  }
  float mx = logit;
#pragma unroll
  for (int off = 16; off > 0; off >>= 1) mx = fmaxf(mx, __shfl_xor(mx, off));
  float p = (lane < NEXP) ? __expf(logit - mx) : 0.f;
  float sum = p;
#pragma unroll
  for (int off = 16; off > 0; off >>= 1) sum += __shfl_xor(sum, off);
  p = p / sum;
  float val = p;
  float chosen = 0.f;
  float selsum = 0.f;
#pragma unroll
  for (int it = 0; it < 4; it++) {
    float v = val;
    int vi = lane;
#pragma unroll
    for (int off = 16; off > 0; off >>= 1) {
      float ov = __shfl_xor(v, off);
      int oi = __shfl_xor(vi, off);
      if (ov > v || (ov == v && oi < vi)) { v = ov; vi = oi; }
    }
    if (lane == vi) { chosen = p; val = -1.f; }
    selsum += v;
  }
  if (lane < NEXP) wout[(size_t)tok * NEXP + lane] = chosen / (selsum + 1e-8f);
}

// ------- batched bucket: blockIdx.y = r (global route R0 + r) -------
__global__ void bucket_kernel(const float* __restrict__ w8,
                              int* __restrict__ lists,
                              int* __restrict__ slotmap,
                              int* __restrict__ counts, int R0) {
  int n = blockIdx.x;
  int gr = R0 + blockIdx.y;
  const float* w = w8 + (size_t)gr * WSTR;
  int* list = lists + (size_t)gr * LSTR;
  int* smap = slotmap + (size_t)gr * LSTR;
  int lane = threadIdx.x; // 64
  int base = 0;
  for (int t0 = 0; t0 < BS; t0 += 64) {
    int tok = t0 + lane;
    bool act = (w[(size_t)tok * NEXP + n] != 0.f);
    unsigned long long mask = __ballot(act);
    int pos = __popcll(mask & ((1ull << lane) - 1ull));
    if (act) {
      list[n * BS + base + pos] = tok;
      smap[n * BS + tok] = base + pos;
    }
    base += __popcll(mask);
  }
  if (lane == 0) counts[gr * NEXP + n] = base;
}

// ---------------- exclusive scan of 32 counts per route ----------------
__global__ void scan32_kernel(const int* __restrict__ counts, int* __restrict__ offs) {
  int r = blockIdx.x;
  int lane = threadIdx.x; // 64
  int c = (lane < NEXP) ? counts[r * NEXP + lane] : 0;
  int s = c;
#pragma unroll
  for (int d = 1; d < NEXP; d <<= 1) {
    int o = __shfl_up(s, d);
    if (lane >= d) s += o;
  }
  if (lane < NEXP) offs[r * NEXP + lane] = s - c;
}

// ---- conflict-free wconv (r9-verified): pitch 66 + XOR swizzle, ALL weights in one
// launch. Blocks 0..12287: features (K=1024,NOUT=512); 12288..24575: restores
// (K=512,NOUT=1024); 24576..24831: W_o (1024,1024). Uniform code + 8.4KB LDS.
#define TCOL(r, c) ((c) ^ (((((r) >> 2)) & 15) << 1))
__global__ __launch_bounds__(256) void wconv_all_kernel(
    const float* __restrict__ F0, const float* __restrict__ F1,
    const float* __restrict__ F2,
    const float* __restrict__ R0w, const float* __restrict__ R1w,
    const float* __restrict__ R2w,
    const float* __restrict__ W_o,
    u16* __restrict__ wbufF, u16* __restrict__ wbufR, u16* __restrict__ woT) {
  __shared__ u16 tile[64][66];
  int bid = blockIdx.x;
  const float* Fe;
  u16* FTe;
  int K, NOUT, n0, k0;
  if (bid < 12288) {
    K = DMODEL; NOUT = RANK;
    n0 = (bid & 7) * 64; k0 = ((bid >> 3) & 15) * 64;
    int z = bid >> 7;
    int p = z >> 5, e = z & 31;
    Fe = ((p == 0) ? F0 : (p == 1) ? F1 : F2) + (size_t)e * K * NOUT;
    FTe = wbufF + (size_t)z * K * NOUT;
  } else if (bid < 24576) {
    int wbid = bid - 12288;
    K = RANK; NOUT = DMODEL;
    n0 = (wbid & 15) * 64; k0 = ((wbid >> 4) & 7) * 64;
    int z = wbid >> 7;
    int p = z >> 5, e = z & 31;
    Fe = ((p == 0) ? R0w : (p == 1) ? R1w : R2w) + (size_t)e * K * NOUT;
    FTe = wbufR + (size_t)z * K * NOUT;
  } else {
    int wbid = bid - 24576;
    K = DMODEL; NOUT = DMODEL;
    n0 = (wbid & 15) * 64; k0 = (wbid >> 4) * 64;
    Fe = W_o; FTe = woT;
  }
  int t = threadIdx.x;
  int kr = t >> 4, nc = (t & 15) * 4;
#pragma unroll
  for (int pp = 0; pp < 4; pp++) {
    int kk = kr + pp * 16;
    float4 v = *reinterpret_cast<const float4*>(Fe + (size_t)(k0 + kk) * NOUT + n0 + nc);
    tile[nc + 0][TCOL(nc + 0, kk)] = bfbits(v.x);
    tile[nc + 1][TCOL(nc + 1, kk)] = bfbits(v.y);
    tile[nc + 2][TCOL(nc + 2, kk)] = bfbits(v.z);
    tile[nc + 3][TCOL(nc + 3, kk)] = bfbits(v.w);
  }
  __syncthreads();
  int nr = t >> 2, c0 = (t & 3) * 16;
  int key = (nr >> 2) & 15;
  const u32* rowp = reinterpret_cast<const u32*>(&tile[nr][0]);
  u32 u[8];
#pragma unroll
  for (int s = 0; s < 8; s++) u[s] = rowp[((c0 >> 1) + s) ^ key];
  u16* dst = FTe + (size_t)(n0 + nr) * K + k0 + c0;
  *reinterpret_cast<uint4*>(dst) = *reinterpret_cast<uint4*>(&u[0]);
  *reinterpret_cast<uint4*>(dst + 8) = *reinterpret_cast<uint4*>(&u[4]);
}

// ------ merged expert GEMM (bf16 MFMA, 256x64 tile: 1 m-block/expert) ------
// Wave owns 64 rows x 64 cols; weight panel read ONCE per expert.
__global__ __launch_bounds__(256) void expert_gemm_mfma(
    const u16* __restrict__ Xb,     // bf16 activations (base)
    const u16* __restrict__ FT,     // [pools*32][NOUT][K] bf16
    const int* __restrict__ lists,  // [8][32][BS]
    const int* __restrict__ counts, // [8][32]
    const int* __restrict__ offsb,  // [8][32]
    u16* __restrict__ Cout,         // compact bf16, + r*4*BS rows
    int R0, int s0, int s1, int s2,
    size_t xstride, int K, int NOUT) {
  int v = blockIdx.y;
  int r = v >> 5, e = v & 31;
  int gr = R0 + r;
  int cnt = counts[gr * NEXP + e];
  int m0 = blockIdx.z * 256;
  if (m0 >= cnt) return;
  int slot = (r == 0) ? s0 : (r == 1) ? s1 : s2;
  int n0 = blockIdx.x * 64;
  const int* list = lists + (size_t)gr * LSTR + (size_t)e * BS;
  __shared__ u16 Xs[256][72];
  __shared__ u16 Fs[64][72];
  __shared__ int toks[256];
  int t = threadIdx.x;
  toks[t] = (m0 + t < cnt) ? list[m0 + t] : -1;
  __syncthreads();
  const u16* X = Xb + (size_t)r * xstride;
  const u16* FTe = FT + ((size_t)(slot * NEXP + e) * NOUT + n0) * K;
  int wave = t >> 6, lane = t & 63;
  int lr = lane & 15, kg = lane >> 4;
  f32x4 acc[4][4] = {};
  int tokr = toks[t];                       // 1 thread per X row
  const u16* xrow = X + (size_t)(tokr < 0 ? 0 : tokr) * K;
  int fri = t >> 2, fc = (t & 3) * 16;
  const u16* frow = FTe + (size_t)fri * K + fc;
  short8 xv[8], fv0, fv1;
  if (tokr >= 0) {
#pragma unroll
    for (int i = 0; i < 8; i++) xv[i] = *reinterpret_cast<const short8*>(xrow + i * 8);
  } else {
#pragma unroll
    for (int i = 0; i < 8; i++) xv[i] = short8{};
  }
  fv0 = *reinterpret_cast<const short8*>(frow);
  fv1 = *reinterpret_cast<const short8*>(frow + 8);
  for (int k0 = 0; k0 < K; k0 += 64) {
    __syncthreads();
#pragma unroll
    for (int i = 0; i < 8; i++)
      *reinterpret_cast<short8*>(&Xs[t][i * 8]) = xv[i];
    *reinterpret_cast<short8*>(&Fs[fri][fc]) = fv0;
    *reinterpret_cast<short8*>(&Fs[fri][fc + 8]) = fv1;
    __syncthreads();
    int kn = k0 + 64;
    if (kn < K) {  // prefetch next tile; latency hides under MFMAs
      if (tokr >= 0) {
#pragma unroll
        for (int i = 0; i < 8; i++)
          xv[i] = *reinterpret_cast<const short8*>(xrow + kn + i * 8);
      }
      fv0 = *reinterpret_cast<const short8*>(frow + kn);
      fv1 = *reinterpret_cast<const short8*>(frow + kn + 8);
    }
#pragma unroll
    for (int kk = 0; kk < 2; kk++) {
#pragma unroll
      for (int ni = 0; ni < 4; ni++) {
        short8 b = *reinterpret_cast<const short8*>(&Fs[ni * 16 + lr][kk * 32 + kg * 8]);
#pragma unroll
        for (int mi = 0; mi < 4; mi++) {
          short8 a = *reinterpret_cast<const short8*>(&Xs[wave * 64 + mi * 16 + lr][kk * 32 + kg * 8]);
          acc[mi][ni] = __builtin_amdgcn_mfma_f32_16x16x32_bf16(a, b, acc[mi][ni], 0, 0, 0);
        }
      }
    }
  }
  int gbase = r * 4 * BS + offsb[gr * NEXP + e] + m0;
#pragma unroll
  for (int mi = 0; mi < 4; mi++) {
#pragma unroll
    for (int j = 0; j < 4; j++) {
      int row = wave * 64 + mi * 16 + kg * 4 + j;
      if (toks[row] < 0) continue;
      u16* crow = Cout + (size_t)(gbase + row) * NOUT + n0;
#pragma unroll
      for (int ni = 0; ni < 4; ni++)
        crow[ni * 16 + lr] = bfbits(acc[mi][ni][j]);
    }
  }
}

// ------- batched gather: blockIdx.y = r; per-route slices at fixed strides -------
template <int NOUT, bool FINAL>
__global__ __launch_bounds__(256) void gather_combine(
    const u16* __restrict__ C,
    const float* __restrict__ w8base,
    const int* __restrict__ slotbase,
    const int* __restrict__ offsbase,
    const float* __restrict__ resid,
    float* __restrict__ outf,
    u16* __restrict__ outbase) {
  int tok = blockIdx.x;
  int r = blockIdx.y;
  const float* wr = w8base + (size_t)r * WSTR;
  const int* smap = slotbase + (size_t)r * LSTR;
  const int* offs = offsbase + r * NEXP;
  const u16* Cr = C + (size_t)r * 4 * BS * NOUT;
  int t = threadIdx.x;
  __shared__ float lw[4];
  __shared__ int ls[4];
  __shared__ int lcnt;
  if (t < 64) {
    float wv = (t < NEXP) ? wr[(size_t)tok * NEXP + t] : 0.f;
    bool act = wv != 0.f;
    unsigned long long mask = __ballot(act);
    int pos = __popcll(mask & ((1ull << t) - 1ull));
    if (act) { ls[pos] = offs[t] + smap[t * BS + tok]; lw[pos] = wv; }
    if (t == 0) lcnt = __popcll(mask);
  }
  __syncthreads();
  if (t < NOUT / 4) {
    float4 s = {0.f, 0.f, 0.f, 0.f};
    int cnt = lcnt;
    for (int k = 0; k < cnt; k++) {
      ushort4 v = reinterpret_cast<const ushort4*>(Cr + (size_t)ls[k] * NOUT)[t];
      float wk = lw[k];
      s.x += wk * b2f(v.x); s.y += wk * b2f(v.y);
      s.z += wk * b2f(v.z); s.w += wk * b2f(v.w);
    }
    if (FINAL) {
      float4 rr = reinterpret_cast<const float4*>(resid + (size_t)tok * NOUT)[t];
      s.x += rr.x; s.y += rr.y; s.z += rr.z; s.w += rr.w;
      reinterpret_cast<float4*>(outf + (size_t)tok * NOUT)[t] = s;
    } else {
      ushort4 o;
      o.x = bfbits(s.x); o.y = bfbits(s.y); o.z = bfbits(s.z); o.w = bfbits(s.w);
      reinterpret_cast<ushort4*>(outbase + (size_t)r * BS * NOUT + (size_t)tok * NOUT)[t] = o;
    }
  }
}

// ---------------- dense bf16 MFMA GEMM: C = A@B (+res), BT = B^T [N][K] ------
template <bool RES>
__global__ __launch_bounds__(256) void dense_gemm_mfma(
    const u16* __restrict__ Ab,
    const u16* __restrict__ BT,
    const float* __restrict__ res,
    float* __restrict__ C, int M, int N, int K) {
  int n0 = blockIdx.x * 64, m0 = blockIdx.y * 64;
  __shared__ u16 Xs[64][72];
  __shared__ u16 Fs[64][72];
  int t = threadIdx.x;
  int wave = t >> 6, lane = t & 63;
  int wm = wave >> 1, wn = wave & 1;
  int lr = lane & 15, kg = lane >> 4;
  f32x4 acc[2][2] = {};
  int srow = t >> 2, sc = (t & 3) * 16;
  const u16* xrow = Ab + (size_t)(m0 + srow) * K + sc;
  const u16* frow = BT + (size_t)(n0 + srow) * K + sc;
  for (int k0 = 0; k0 < K; k0 += 64) {
    short8 xv0 = *reinterpret_cast<const short8*>(xrow + k0);
    short8 xv1 = *reinterpret_cast<const short8*>(xrow + k0 + 8);
    short8 fv0 = *reinterpret_cast<const short8*>(frow + k0);
    short8 fv1 = *reinterpret_cast<const short8*>(frow + k0 + 8);
    __syncthreads();
    *reinterpret_cast<short8*>(&Xs[srow][sc]) = xv0;
    *reinterpret_cast<short8*>(&Xs[srow][sc + 8]) = xv1;
    *reinterpret_cast<short8*>(&Fs[srow][sc]) = fv0;
    *reinterpret_cast<short8*>(&Fs[srow][sc + 8]) = fv1;
    __syncthreads();
#pragma unroll
    for (int kk = 0; kk < 2; kk++) {
      short8 a0 = *reinterpret_cast<const short8*>(&Xs[wm * 32 + lr][kk * 32 + kg * 8]);
      short8 a1 = *reinterpret_cast<const short8*>(&Xs[wm * 32 + 16 + lr][kk * 32 + kg * 8]);
      short8 b0 = *reinterpret_cast<const short8*>(&Fs[wn * 32 + lr][kk * 32 + kg * 8]);
      short8 b1 = *reinterpret_cast<const short8*>(&Fs[wn * 32 + 16 + lr][kk * 32 + kg * 8]);
      acc[0][0] = __builtin_amdgcn_mfma_f32_16x16x32_bf16(a0, b0, acc[0][0], 0, 0, 0);
      acc[0][1] = __builtin_amdgcn_mfma_f32_16x16x32_bf16(a0, b1, acc[0][1], 0, 0, 0);
      acc[1][0] = __builtin_amdgcn_mfma_f32_16x16x32_bf16(a1, b0, acc[1][0], 0, 0, 0);
      acc[1][1] = __builtin_amdgcn_mfma_f32_16x16x32_bf16(a1, b1, acc[1][1], 0, 0, 0);
    }
  }
#pragma unroll
  for (int mi = 0; mi < 2; mi++) {
#pragma unroll
    for (int j = 0; j < 4; j++) {
      int row = m0 + wm * 32 + mi * 16 + kg * 4 + j;
#pragma unroll
      for (int ni = 0; ni < 2; ni++) {
        int col = n0 + wn * 32 + ni * 16 + lr;
        float v = acc[mi][ni][j];
        if (RES) v += res[(size_t)row * N + col];
        C[(size_t)row * N + col] = v;
      }
    }
  }
}

// ---------------- causal flash attention (bf16 MFMA, bf16 inputs) ----------------
__global__ __launch_bounds__(256) void attn_mfma(const u16* __restrict__ Qb,
                                                 const u16* __restrict__ Kb,
                                                 const u16* __restrict__ Vb,
                                                 u16* __restrict__ Ob) {
  int qt = (gridDim.x - 1 - blockIdx.x) * 64;  // long blocks first
  int h = blockIdx.y, b = blockIdx.z;
  int t = threadIdx.x;
  int w = t >> 6, lane = t & 63;
  int lr = lane & 15, kg = lane >> 4;
  __shared__ u16 Ks[64][72];
  __shared__ u16 Vs[64][66];
  __shared__ u16 Ps[4][16][72];
  size_t base = (size_t)(b * SEQ) * DMODEL + (size_t)h * DHEAD;
  const u16* qrow = Qb + base + (size_t)(qt + w * 16 + lr) * DMODEL + kg * 8;
  short8 aq0 = *reinterpret_cast<const short8*>(qrow);
  short8 aq1 = *reinterpret_cast<const short8*>(qrow + 32);
  float m[4], l[4];
#pragma unroll
  for (int j = 0; j < 4; j++) { m[j] = -1e30f; l[j] = 0.f; }
  f32x4 acc_o[4] = {};
  for (int kt = 0; kt <= qt; kt += 64) {
    __syncthreads();
    {
      int r = t >> 2, c0 = (t & 3) * 16;
      const u16* krow = Kb + base + (size_t)(kt + r) * DMODEL + c0;
      *reinterpret_cast<short8*>(&Ks[r][c0]) = *reinterpret_cast<const short8*>(krow);
      *reinterpret_cast<short8*>(&Ks[r][c0 + 8]) = *reinterpret_cast<const short8*>(krow + 8);
      int d = lane;
      int r0v = w * 16;
      const u16* vcol = Vb + base + (size_t)(kt + r0v) * DMODEL + d;
#pragma unroll
      for (int i = 0; i < 16; i++)
        Vs[d][r0v + i] = vcol[(size_t)i * DMODEL];
    }
    __syncthreads();
    f32x4 s[4] = {};
#pragma unroll
    for (int c = 0; c < 4; c++) {
      short8 bk0 = *reinterpret_cast<const short8*>(&Ks[c * 16 + lr][kg * 8]);
      short8 bk1 = *reinterpret_cast<const short8*>(&Ks[c * 16 + lr][32 + kg * 8]);
      s[c] = __builtin_amdgcn_mfma_f32_16x16x32_bf16(aq0, bk0, s[c], 0, 0, 0);
      s[c] = __builtin_amdgcn_mfma_f32_16x16x32_bf16(aq1, bk1, s[c], 0, 0, 0);
    }
#pragma unroll
    for (int c = 0; c < 4; c++)
#pragma unroll
      for (int j = 0; j < 4; j++) s[c][j] *= 0.125f;
    if (kt == qt) {
#pragma unroll
      for (int c = 0; c < 4; c++)
#pragma unroll
        for (int j = 0; j < 4; j++)
          if (c * 16 + lr > w * 16 + kg * 4 + j) s[c][j] = -1e30f;
    }
    float mt[4];
#pragma unroll
    for (int j = 0; j < 4; j++)
      mt[j] = fmaxf(fmaxf(s[0][j], s[1][j]), fmaxf(s[2][j], s[3][j]));
#pragma unroll
    for (int off = 1; off < 16; off <<= 1)
#pragma unroll
      for (int j = 0; j < 4; j++) mt[j] = fmaxf(mt[j], __shfl_xor(mt[j], off));
    float corr[4];
#pragma unroll
    for (int j = 0; j < 4; j++) {
      float mn = fmaxf(m[j], mt[j]);
      corr[j] = __expf(m[j] - mn);
      m[j] = mn;
      l[j] *= corr[j];
    }
#pragma unroll
    for (int di = 0; di < 4; di++)
#pragma unroll
      for (int j = 0; j < 4; j++) acc_o[di][j] *= corr[j];
    float ps[4] = {0.f, 0.f, 0.f, 0.f};
#pragma unroll
    for (int c = 0; c < 4; c++)
#pragma unroll
      for (int j = 0; j < 4; j++) {
        float p = __expf(s[c][j] - m[j]);
        ps[j] += p;
        s[c][j] = p;
      }
#pragma unroll
    for (int off = 1; off < 16; off <<= 1)
#pragma unroll
      for (int j = 0; j < 4; j++) ps[j] += __shfl_xor(ps[j], off);
#pragma unroll
    for (int j = 0; j < 4; j++) l[j] += ps[j];
#pragma unroll
    for (int c = 0; c < 4; c++)
#pragma unroll
      for (int j = 0; j < 4; j++)
        Ps[w][kg * 4 + j][c * 16 + lr] = bfbits(s[c][j]);
    short8 pa0 = *reinterpret_cast<const short8*>(&Ps[w][lr][kg * 8]);
    short8 pa1 = *reinterpret_cast<const short8*>(&Ps[w][lr][32 + kg * 8]);
#pragma unroll
    for (int di = 0; di < 4; di++) {
      short8 bv0 = *reinterpret_cast<const short8*>(&Vs[di * 16 + lr][kg * 8]);
      short8 bv1 = *reinterpret_cast<const short8*>(&Vs[di * 16 + lr][32 + kg * 8]);
      acc_o[di] = __builtin_amdgcn_mfma_f32_16x16x32_bf16(pa0, bv0, acc_o[di], 0, 0, 0);
      acc_o[di] = __builtin_amdgcn_mfma_f32_16x16x32_bf16(pa1, bv1, acc_o[di], 0, 0, 0);
    }
  }
#pragma unroll
  for (int j = 0; j < 4; j++) {
    float inv = 1.f / l[j];
    size_t rowoff = base + (size_t)(qt + w * 16 + kg * 4 + j) * DMODEL;
#pragma unroll
    for (int di = 0; di < 4; di++)
      Ob[rowoff + di * 16 + lr] = bfbits(acc_o[di][j] * inv);
  }
}

// ---------------- launch ----------------
extern "C" void kernel_launch(void* const* d_in, const int* in_sizes, int n_in,
                              void* d_out, int out_size, void* d_ws, size_t ws_size,
                              hipStream_t stream) {
  const float* x    = (const float*)d_in[0];
  const float* f_qk = (const float*)d_in[1];
  const float* f_v  = (const float*)d_in[2];
  const float* r_qk = (const float*)d_in[3];
  const float* r_v  = (const float*)d_in[4];
  const float* f_kn = (const float*)d_in[5];
  const float* r_kn = (const float*)d_in[6];
  const float* nemb = (const float*)d_in[7];
  const float* W_all = (const float*)d_in[8];
  const float* b_all = (const float*)d_in[9];
  const float* W_fk  = (const float*)d_in[10];
  const float* b_fk  = (const float*)d_in[11];
  const float* W_rk  = (const float*)d_in[12];
  const float* b_rk  = (const float*)d_in[13];
  const float* W_o   = (const float*)d_in[14];
  const float* ln1s  = (const float*)d_in[15];
  const float* ln1b  = (const float*)d_in[16];
  const float* ln2s  = (const float*)d_in[17];
  const float* ln2b  = (const float*)d_in[18];

  float* ws = (float*)d_ws;
  size_t off = 0;
  auto alloc = [&](size_t nf) { float* p = ws + off; off += nf; return p; };
  float* nx      = alloc((size_t)BS * DMODEL);
  float* nx2     = alloc((size_t)BS * DMODEL);
  float* embn    = alloc(6 * NEXP * DSP);
  float* h_all   = alloc((size_t)BS * HALL_N);
  float* hk2     = alloc((size_t)2 * BS * DSP);    // h_fk2 | h_rk2 contiguous
  float* w8      = alloc((size_t)8 * BS * NEXP);
  float* x1      = alloc((size_t)BS * DMODEL);
  float* compactFf = alloc((size_t)3 * 2 * BS * RANK);    // 3 routes x 8192 x 512 u16
  float* compactRf = alloc((size_t)3 * 2 * BS * DMODEL);  // 3 routes x 8192 x 1024 u16 (+partials)
  int* lists   = (int*)(ws + off); off += (size_t)8 * NEXP * BS;
  int* slotmap = (int*)(ws + off); off += (size_t)8 * NEXP * BS;
  int* counts  = (int*)(ws + off); off += 8 * NEXP;
  int* offsb   = (int*)(ws + off); off += 8 * NEXP;
  u16* nxb  = (u16*)(ws + off); off += (size_t)BS * DMODEL / 2;
  u16* fqb  = (u16*)(ws + off); off += (size_t)3 * BS * RANK / 2;  // fqb|fkb|fvb contiguous
  u16* fnb  = (u16*)(ws + off); off += (size_t)BS * RANK / 2;
  u16* Qbb  = (u16*)(ws + off); off += (size_t)3 * BS * DMODEL / 2; // Q|K|V contiguous
  u16* attnOb = (u16*)(ws + off); off += (size_t)BS * DMODEL / 2;
  u16* woT  = (u16*)(ws + off); off += (size_t)DMODEL * DMODEL / 2;
  u16* wbufF = (u16*)(ws + off); off += (size_t)3 * NEXP * DMODEL * RANK / 2; // f_qk|f_v|f_kn
  u16* wbufR = (u16*)(ws + off); off += (size_t)3 * NEXP * RANK * DMODEL / 2; // r_qk|r_v|r_kn
  u16* compactF = (u16*)compactFf;
  u16* compactR = (u16*)compactRf;
  u16* fkb = fqb + (size_t)BS * RANK;
  u16* fvb = fkb + (size_t)BS * RANK;
  u16* Kbb = Qbb + (size_t)BS * DMODEL;
  u16* Vbb = Kbb + (size_t)BS * DMODEL;
  float* h_fk2 = hk2;
  float* partA = compactRf;  // W_all partials: 4*BS*384 = 3.1M fl < 12.6M
  float* partK = compactRf;  // W_fk+W_rk partials: 16*BS*64 = 2.1M fl
  (void)fkb; (void)fvb; (void)Kbb; (void)Vbb;

  // ---- weights & norms (no deps): single merged wconv for all 7 weight tensors ----
  embnorm_kernel<<<6 * NEXP, DSP, 0, stream>>>(nemb, embn);
  wconv_all_kernel<<<24832, 256, 0, stream>>>(f_qk, f_v, f_kn, r_qk, r_v, r_kn,
                                              W_o, wbufF, wbufR, woT);

  // ---- attention circuit ----
  ln_kernel<<<BS, 256, 0, stream>>>(x, ln1s, ln1b, nx, nxb);
  gemm_splitk<<<dim3(HALL_N / 64, BS / 64, 4), 256, 0, stream>>>(
      nx, W_all, partA, BS, HALL_N, DMODEL, DMODEL / 4);
  reduce_bias_kernel<<<(BS * HALL_N / 4 + 255) / 256, 256, 0, stream>>>(
      partA, b_all, h_all, BS * HALL_N, HALL_N, 4);

  route_kernel<<<dim3(BS, 6), 64, 0, stream>>>(h_all, DSP, HALL_N, embn, 0, w8);
  bucket_kernel<<<dim3(NEXP, 6), 64, 0, stream>>>(w8, lists, slotmap, counts, 0);
  scan32_kernel<<<6, 64, 0, stream>>>(counts, offsb);

  // merged feature GEMM: routes 0,1,2 (slots f_qk,f_qk,f_v), 256-row m-tile
  expert_gemm_mfma<<<dim3(RANK / 64, 3 * NEXP, BS / 256), 256, 0, stream>>>(
      nxb, wbufF, lists, counts, offsb, compactF,
      0, 0, 0, 1, 0, DMODEL, RANK);
  gather_combine<RANK, false><<<dim3(BS, 3), 256, 0, stream>>>(
      compactF, w8, slotmap, offsb, nullptr, nullptr, fqb);

  // merged restore GEMM: routes 3,4,5 (slots r_qk,r_qk,r_v), X = fqb|fkb|fvb
  expert_gemm_mfma<<<dim3(DMODEL / 64, 3 * NEXP, BS / 256), 256, 0, stream>>>(
      fqb, wbufR, lists, counts, offsb, compactR,
      3, 0, 0, 1, (size_t)BS * RANK, RANK, DMODEL);
  gather_combine<DMODEL, false><<<dim3(BS, 3), 256, 0, stream>>>(
      compactR, w8 + 3 * WSTR, slotmap + 3 * LSTR, offsb + 3 * NEXP,
      nullptr, nullptr, Qbb);

  attn_mfma<<<dim3(SEQ / 64, NHEAD, BATCH), 256, 0, stream>>>(Qbb, Kbb, Vbb, attnOb);

  dense_gemm_mfma<true><<<dim3(DMODEL / 64, BS / 64), 256, 0, stream>>>(
      attnOb, woT, x, x1, BS, DMODEL, DMODEL);

  // ---- knowledge circuit ----
  ln_kernel<<<BS, 256, 0, stream>>>(x1, ln2s, ln2b, nx2, nxb);
  gemm_splitk2<<<dim3(1, BS / 64, 16), 256, 0, stream>>>(
      nx2, W_fk, W_rk, partK, BS, DSP, DMODEL, DMODEL / 8);
  reduce_bias2_kernel<<<dim3((BS * DSP / 4 + 255) / 256, 2), 256, 0, stream>>>(
      partK, b_fk, b_rk, h_fk2, BS * DSP, DSP, 8);
  route_kernel<<<dim3(BS, 2), 64, 0, stream>>>(h_fk2, (size_t)BS * DSP, DSP, embn, 6, w8);
  bucket_kernel<<<dim3(NEXP, 2), 64, 0, stream>>>(w8, lists, slotmap, counts, 6);
  scan32_kernel<<<2, 64, 0, stream>>>(counts + 6 * NEXP, offsb + 6 * NEXP);

  expert_gemm_mfma<<<dim3(RANK / 64, NEXP, BS / 256), 256, 0, stream>>>(
      nxb, wbufF, lists, counts, offsb, compactF,
      6, 2, 2, 2, 0, DMODEL, RANK);
  gather_combine<RANK, false><<<dim3(BS, 1), 256, 0, stream>>>(
      compactF, w8 + 6 * WSTR, slotmap + 6 * LSTR, offsb + 6 * NEXP,
      nullptr, nullptr, fnb);
  expert_gemm_mfma<<<dim3(DMODEL / 64, NEXP, BS / 256), 256, 0, stream>>>(
      fnb, wbufR, lists, counts, offsb, compactR,
      7, 2, 2, 2, 0, RANK, DMODEL);
  // d_out = x1 + restore(featN)
  gather_combine<DMODEL, true><<<dim3(BS, 1), 256, 0, stream>>>(
      compactR, w8 + 7 * WSTR, slotmap + 7 * LSTR, offsb + 7 * NEXP,
      x1, (float*)d_out, nullptr);
}

// Round 14
// 520.354 us; speedup vs baseline: 1.1325x; 1.1325x over previous
//
#include <hip/hip_runtime.h>
#include <hip/hip_bf16.h>
#include <cstdint>

#define BS     2048   // B*S tokens
#define DMODEL 1024
#define RANK   512
#define NEXP   32
#define DSP    64
#define NHEAD  16
#define DHEAD  64
#define SEQ    1024
#define BATCH  2
#define HALL_N 384    // 6*DSP
#define WSTR   ((size_t)BS * NEXP)
#define LSTR   ((size_t)NEXP * BS)

typedef unsigned short u16;
typedef unsigned int u32;
typedef __attribute__((ext_vector_type(8))) short short8;
typedef __attribute__((ext_vector_type(4))) float f32x4;

__device__ __forceinline__ u16 bfbits(float x) {
  __hip_bfloat16 h = __float2bfloat16(x);
  return __builtin_bit_cast(u16, h);
}
__device__ __forceinline__ float b2f(u16 u) {
  unsigned int x = (unsigned int)u << 16;
  return __builtin_bit_cast(float, x);
}

// ---------------- LayerNorm (token per block, 256 thr, float4), fp32 + bf16 out ----
__global__ void ln_kernel(const float* __restrict__ x,
                          const float* __restrict__ sc,
                          const float* __restrict__ bi,
                          float* __restrict__ out,
                          u16* __restrict__ outb) {
  int tok = blockIdx.x;
  int t = threadIdx.x; // 256
  const float4* xr = reinterpret_cast<const float4*>(x + (size_t)tok * DMODEL);
  float4 v = xr[t];
  float s = v.x + v.y + v.z + v.w;
  float q = v.x * v.x + v.y * v.y + v.z * v.z + v.w * v.w;
#pragma unroll
  for (int off = 32; off > 0; off >>= 1) {
    s += __shfl_xor(s, off);
    q += __shfl_xor(q, off);
  }
  __shared__ float red[8];
  int wid = t >> 6;
  if ((t & 63) == 0) { red[wid] = s; red[4 + wid] = q; }
  __syncthreads();
  s = red[0] + red[1] + red[2] + red[3];
  q = red[4] + red[5] + red[6] + red[7];
  float mu = s * (1.f / DMODEL);
  float var = q * (1.f / DMODEL) - mu * mu;
  float inv = rsqrtf(var + 1e-6f);
  float4 scv = reinterpret_cast<const float4*>(sc)[t];
  float4 biv = reinterpret_cast<const float4*>(bi)[t];
  float4 r;
  r.x = (v.x - mu) * inv * scv.x + biv.x;
  r.y = (v.y - mu) * inv * scv.y + biv.y;
  r.z = (v.z - mu) * inv * scv.z + biv.z;
  r.w = (v.w - mu) * inv * scv.w + biv.w;
  reinterpret_cast<float4*>(out + (size_t)tok * DMODEL)[t] = r;
  ushort4 ob;
  ob.x = bfbits(r.x); ob.y = bfbits(r.y); ob.z = bfbits(r.z); ob.w = bfbits(r.w);
  reinterpret_cast<ushort4*>(outb + (size_t)tok * DMODEL)[t] = ob;
}

// ---------------- emb row L2-normalize ----------------
__global__ void embnorm_kernel(const float* __restrict__ e, float* __restrict__ o) {
  int row = blockIdx.x;
  int lane = threadIdx.x; // 64
  float v = e[row * DSP + lane];
  float q = v * v;
#pragma unroll
  for (int off = 32; off > 0; off >>= 1) q += __shfl_xor(q, off);
  o[row * DSP + lane] = v / (sqrtf(q) + 1e-8f);
}

// ---------------- fp32 split-K GEMM: part[ks] = A[M,Kc]@B[Kc,N] ----------------
__global__ __launch_bounds__(256) void gemm_splitk(const float* __restrict__ A,
                                                   const float* __restrict__ Bm,
                                                   float* __restrict__ part,
                                                   int M, int N, int K, int kchunk) {
  __shared__ float As[16][65];
  __shared__ float Bs[16][64];
  int n0 = blockIdx.x * 64;
  int m0 = blockIdx.y * 64;
  int kbeg = blockIdx.z * kchunk;
  int t = threadIdx.x;
  int tx = t & 15, ty = t >> 4;
  float c[4][4] = {};
  for (int k0 = kbeg; k0 < kbeg + kchunk; k0 += 16) {
#pragma unroll
    for (int i = 0; i < 4; i++) {
      int idx = t + i * 256;
      int m = idx >> 4, kk = idx & 15;
      As[kk][m] = A[(size_t)(m0 + m) * K + k0 + kk];
    }
#pragma unroll
    for (int i = 0; i < 4; i++) {
      int idx = t + i * 256;
      int kk = idx >> 6, nn = idx & 63;
      Bs[kk][nn] = Bm[(size_t)(k0 + kk) * N + n0 + nn];
    }
    __syncthreads();
#pragma unroll
    for (int kk = 0; kk < 16; kk++) {
      float a[4], b[4];
#pragma unroll
      for (int i = 0; i < 4; i++) a[i] = As[kk][ty + i * 16];
#pragma unroll
      for (int j = 0; j < 4; j++) b[j] = Bs[kk][tx + j * 16];
#pragma unroll
      for (int i = 0; i < 4; i++)
#pragma unroll
        for (int j = 0; j < 4; j++) c[i][j] += a[i] * b[j];
    }
    __syncthreads();
  }
  float* po = part + (size_t)blockIdx.z * M * N;
#pragma unroll
  for (int i = 0; i < 4; i++)
#pragma unroll
    for (int j = 0; j < 4; j++)
      po[(size_t)(m0 + ty + i * 16) * N + n0 + tx + j * 16] = c[i][j];
}

// ---------------- batched split-K for W_fk+W_rk (z = wsel*8 + ks) ----------------
__global__ __launch_bounds__(256) void gemm_splitk2(const float* __restrict__ A,
                                                    const float* __restrict__ B0,
                                                    const float* __restrict__ B1,
                                                    float* __restrict__ part,
                                                    int M, int N, int K, int kchunk) {
  __shared__ float As[16][65];
  __shared__ float Bs[16][64];
  int wsel = blockIdx.z >> 3, ks = blockIdx.z & 7;
  const float* Bm = wsel ? B1 : B0;
  int n0 = blockIdx.x * 64;
  int m0 = blockIdx.y * 64;
  int kbeg = ks * kchunk;
  int t = threadIdx.x;
  int tx = t & 15, ty = t >> 4;
  float c[4][4] = {};
  for (int k0 = kbeg; k0 < kbeg + kchunk; k0 += 16) {
#pragma unroll
    for (int i = 0; i < 4; i++) {
      int idx = t + i * 256;
      int m = idx >> 4, kk = idx & 15;
      As[kk][m] = A[(size_t)(m0 + m) * K + k0 + kk];
    }
#pragma unroll
    for (int i = 0; i < 4; i++) {
      int idx = t + i * 256;
      int kk = idx >> 6, nn = idx & 63;
      Bs[kk][nn] = Bm[(size_t)(k0 + kk) * N + n0 + nn];
    }
    __syncthreads();
#pragma unroll
    for (int kk = 0; kk < 16; kk++) {
      float a[4], b[4];
#pragma unroll
      for (int i = 0; i < 4; i++) a[i] = As[kk][ty + i * 16];
#pragma unroll
      for (int j = 0; j < 4; j++) b[j] = Bs[kk][tx + j * 16];
#pragma unroll
      for (int i = 0; i < 4; i++)
#pragma unroll
        for (int j = 0; j < 4; j++) c[i][j] += a[i] * b[j];
    }
    __syncthreads();
  }
  float* po = part + (size_t)blockIdx.z * M * N;
#pragma unroll
  for (int i = 0; i < 4; i++)
#pragma unroll
    for (int j = 0; j < 4; j++)
      po[(size_t)(m0 + ty + i * 16) * N + n0 + tx + j * 16] = c[i][j];
}

// ---------------- split-K reduce + bias ----------------
__global__ void reduce_bias_kernel(const float* __restrict__ part,
                                   const float* __restrict__ bias,
                                   float* __restrict__ out,
                                   int MN, int N, int KS) {
  int i = blockIdx.x * 256 + threadIdx.x;
  if (i * 4 >= MN) return;
  float4 s = reinterpret_cast<const float4*>(part)[i];
  for (int ks = 1; ks < KS; ks++) {
    float4 p = reinterpret_cast<const float4*>(part + (size_t)ks * MN)[i];
    s.x += p.x; s.y += p.y; s.z += p.z; s.w += p.w;
  }
  int col = (i * 4) % N;
  float4 b = *reinterpret_cast<const float4*>(bias + col);
  s.x += b.x; s.y += b.y; s.z += b.z; s.w += b.w;
  reinterpret_cast<float4*>(out)[i] = s;
}

// ---------------- batched reduce for W_fk/W_rk (blockIdx.y = wsel) ----------------
__global__ void reduce_bias2_kernel(const float* __restrict__ part,
                                    const float* __restrict__ bias0,
                                    const float* __restrict__ bias1,
                                    float* __restrict__ out,
                                    int MN, int N, int KS) {
  int wsel = blockIdx.y;
  const float* p0 = part + (size_t)wsel * KS * MN;
  const float* bias = wsel ? bias1 : bias0;
  float* o = out + (size_t)wsel * MN;
  int i = blockIdx.x * 256 + threadIdx.x;
  if (i * 4 >= MN) return;
  float4 s = reinterpret_cast<const float4*>(p0)[i];
  for (int ks = 1; ks < KS; ks++) {
    float4 p = reinterpret_cast<const float4*>(p0 + (size_t)ks * MN)[i];
    s.x += p.x; s.y += p.y; s.z += p.z; s.w += p.w;
  }
  int col = (i * 4) % N;
  float4 b = *reinterpret_cast<const float4*>(bias + col);
  s.x += b.x; s.y += b.y; s.z += b.z; s.w += b.w;
  reinterpret_cast<float4*>(o)[i] = s;
}

// ------- batched routing: blockIdx.y = r, global route = R0 + r -------
__global__ void route_kernel(const float* __restrict__ h, size_t roff, int ldh,
                             const float* __restrict__ embn, int R0,
                             float* __restrict__ w8) {
  int tok = blockIdx.x;
  int r = blockIdx.y;
  int gr = R0 + r;
  int pool = (gr < 2) ? 0 : (gr < 3) ? 1 : (gr < 5) ? 2 : (gr < 6) ? 3 : (gr < 7) ? 4 : 5;
  const float* e = embn + (size_t)pool * NEXP * DSP;
  const float* hr = h + (size_t)r * roff;
  float* wout = w8 + (size_t)gr * WSTR;
  int lane = threadIdx.x; // 64
  __shared__ float hs[DSP];
  __shared__ float es[NEXP * DSP];
  hs[lane] = hr[(size_t)tok * ldh + lane];
#pragma unroll
  for (int i = 0; i < NEXP * DSP / 64; i++) es[lane + i * 64] = e[lane + i * 64];
  __syncthreads();
  float logit = -1e30f;
  if (lane < NEXP) {
    float s = 0.f;
#pragma unroll
    for (int d = 0; d < DSP; d++) s += hs[d] * es[lane * DSP + d];
    logit = s;
  }
  float mx = logit;
#pragma unroll
  for (int off = 16; off > 0; off >>= 1) mx = fmaxf(mx, __shfl_xor(mx, off));
  float p = (lane < NEXP) ? __expf(logit - mx) : 0.f;
  float sum = p;
#pragma unroll
  for (int off = 16; off > 0; off >>= 1) sum += __shfl_xor(sum, off);
  p = p / sum;
  float val = p;
  float chosen = 0.f;
  float selsum = 0.f;
#pragma unroll
  for (int it = 0; it < 4; it++) {
    float v = val;
    int vi = lane;
#pragma unroll
    for (int off = 16; off > 0; off >>= 1) {
      float ov = __shfl_xor(v, off);
      int oi = __shfl_xor(vi, off);
      if (ov > v || (ov == v && oi < vi)) { v = ov; vi = oi; }
    }
    if (lane == vi) { chosen = p; val = -1.f; }
    selsum += v;
  }
  if (lane < NEXP) wout[(size_t)tok * NEXP + lane] = chosen / (selsum + 1e-8f);
}

// ------- batched bucket: blockIdx.y = r (global route R0 + r) -------
__global__ void bucket_kernel(const float* __restrict__ w8,
                              int* __restrict__ lists,
                              int* __restrict__ slotmap,
                              int* __restrict__ counts, int R0) {
  int n = blockIdx.x;
  int gr = R0 + blockIdx.y;
  const float* w = w8 + (size_t)gr * WSTR;
  int* list = lists + (size_t)gr * LSTR;
  int* smap = slotmap + (size_t)gr * LSTR;
  int lane = threadIdx.x; // 64
  int base = 0;
  for (int t0 = 0; t0 < BS; t0 += 64) {
    int tok = t0 + lane;
    bool act = (w[(size_t)tok * NEXP + n] != 0.f);
    unsigned long long mask = __ballot(act);
    int pos = __popcll(mask & ((1ull << lane) - 1ull));
    if (act) {
      list[n * BS + base + pos] = tok;
      smap[n * BS + tok] = base + pos;
    }
    base += __popcll(mask);
  }
  if (lane == 0) counts[gr * NEXP + n] = base;
}

// ---------------- exclusive scan of 32 counts per route ----------------
__global__ void scan32_kernel(const int* __restrict__ counts, int* __restrict__ offs) {
  int r = blockIdx.x;
  int lane = threadIdx.x; // 64
  int c = (lane < NEXP) ? counts[r * NEXP + lane] : 0;
  int s = c;
#pragma unroll
  for (int d = 1; d < NEXP; d <<= 1) {
    int o = __shfl_up(s, d);
    if (lane >= d) s += o;
  }
  if (lane < NEXP) offs[r * NEXP + lane] = s - c;
}

// ---- conflict-free wconv (r9-verified): pitch 66 + XOR swizzle, ALL weights in one
// launch. Blocks 0..12287: features (K=1024,NOUT=512); 12288..24575: restores
// (K=512,NOUT=1024); 24576..24831: W_o (1024,1024). Uniform code + 8.4KB LDS.
#define TCOL(r, c) ((c) ^ (((((r) >> 2)) & 15) << 1))
__global__ __launch_bounds__(256) void wconv_all_kernel(
    const float* __restrict__ F0, const float* __restrict__ F1,
    const float* __restrict__ F2,
    const float* __restrict__ R0w, const float* __restrict__ R1w,
    const float* __restrict__ R2w,
    const float* __restrict__ W_o,
    u16* __restrict__ wbufF, u16* __restrict__ wbufR, u16* __restrict__ woT) {
  __shared__ u16 tile[64][66];
  int bid = blockIdx.x;
  const float* Fe;
  u16* FTe;
  int K, NOUT, n0, k0;
  if (bid < 12288) {
    K = DMODEL; NOUT = RANK;
    n0 = (bid & 7) * 64; k0 = ((bid >> 3) & 15) * 64;
    int z = bid >> 7;
    int p = z >> 5, e = z & 31;
    Fe = ((p == 0) ? F0 : (p == 1) ? F1 : F2) + (size_t)e * K * NOUT;
    FTe = wbufF + (size_t)z * K * NOUT;
  } else if (bid < 24576) {
    int wbid = bid - 12288;
    K = RANK; NOUT = DMODEL;
    n0 = (wbid & 15) * 64; k0 = ((wbid >> 4) & 7) * 64;
    int z = wbid >> 7;
    int p = z >> 5, e = z & 31;
    Fe = ((p == 0) ? R0w : (p == 1) ? R1w : R2w) + (size_t)e * K * NOUT;
    FTe = wbufR + (size_t)z * K * NOUT;
  } else {
    int wbid = bid - 24576;
    K = DMODEL; NOUT = DMODEL;
    n0 = (wbid & 15) * 64; k0 = (wbid >> 4) * 64;
    Fe = W_o; FTe = woT;
  }
  int t = threadIdx.x;
  int kr = t >> 4, nc = (t & 15) * 4;
#pragma unroll
  for (int pp = 0; pp < 4; pp++) {
    int kk = kr + pp * 16;
    float4 v = *reinterpret_cast<const float4*>(Fe + (size_t)(k0 + kk) * NOUT + n0 + nc);
    tile[nc + 0][TCOL(nc + 0, kk)] = bfbits(v.x);
    tile[nc + 1][TCOL(nc + 1, kk)] = bfbits(v.y);
    tile[nc + 2][TCOL(nc + 2, kk)] = bfbits(v.z);
    tile[nc + 3][TCOL(nc + 3, kk)] = bfbits(v.w);
  }
  __syncthreads();
  int nr = t >> 2, c0 = (t & 3) * 16;
  int key = (nr >> 2) & 15;
  const u32* rowp = reinterpret_cast<const u32*>(&tile[nr][0]);
  u32 u[8];
#pragma unroll
  for (int s = 0; s < 8; s++) u[s] = rowp[((c0 >> 1) + s) ^ key];
  u16* dst = FTe + (size_t)(n0 + nr) * K + k0 + c0;
  *reinterpret_cast<uint4*>(dst) = *reinterpret_cast<uint4*>(&u[0]);
  *reinterpret_cast<uint4*>(dst + 8) = *reinterpret_cast<uint4*>(&u[4]);
}

// ---------------- merged expert GEMM (bf16 MFMA, 128x64, multi-route) ----------------
__global__ __launch_bounds__(256) void expert_gemm_mfma(
    const u16* __restrict__ Xb,     // bf16 activations (base)
    const u16* __restrict__ FT,     // [pools*32][NOUT][K] bf16
    const int* __restrict__ lists,  // [8][32][BS]
    const int* __restrict__ counts, // [8][32]
    const int* __restrict__ offsb,  // [8][32]
    u16* __restrict__ Cout,         // compact bf16, + r*4*BS rows
    int R0, int s0, int s1, int s2,
    size_t xstride, int K, int NOUT) {
  int v = blockIdx.y;
  int r = v >> 5, e = v & 31;
  int gr = R0 + r;
  int cnt = counts[gr * NEXP + e];
  int m0 = blockIdx.z * 128;
  if (m0 >= cnt) return;
  int slot = (r == 0) ? s0 : (r == 1) ? s1 : s2;
  int n0 = blockIdx.x * 64;
  const int* list = lists + (size_t)gr * LSTR + (size_t)e * BS;
  __shared__ u16 Xs[128][72];
  __shared__ u16 Fs[64][72];
  __shared__ int toks[128];
  int t = threadIdx.x;
  if (t < 128) toks[t] = (m0 + t < cnt) ? list[m0 + t] : -1;
  __syncthreads();
  const u16* X = Xb + (size_t)r * xstride;
  const u16* FTe = FT + ((size_t)(slot * NEXP + e) * NOUT + n0) * K;
  int wave = t >> 6, lane = t & 63;
  int wm = wave >> 1, wn = wave & 1;
  int lr = lane & 15, kg = lane >> 4;
  f32x4 acc[4][2] = {};
  int xri = t >> 1, xc = (t & 1) * 32;
  int tokr = toks[xri];
  const u16* xrow = X + (size_t)(tokr < 0 ? 0 : tokr) * K + xc;
  int fri = t >> 2, fc = (t & 3) * 16;
  const u16* frow = FTe + (size_t)fri * K + fc;
  short8 xv0 = {}, xv1 = {}, xv2 = {}, xv3 = {}, fv0, fv1;
  if (tokr >= 0) {
    xv0 = *reinterpret_cast<const short8*>(xrow);
    xv1 = *reinterpret_cast<const short8*>(xrow + 8);
    xv2 = *reinterpret_cast<const short8*>(xrow + 16);
    xv3 = *reinterpret_cast<const short8*>(xrow + 24);
  }
  fv0 = *reinterpret_cast<const short8*>(frow);
  fv1 = *reinterpret_cast<const short8*>(frow + 8);
  for (int k0 = 0; k0 < K; k0 += 64) {
    __syncthreads();
    *reinterpret_cast<short8*>(&Xs[xri][xc]) = xv0;
    *reinterpret_cast<short8*>(&Xs[xri][xc + 8]) = xv1;
    *reinterpret_cast<short8*>(&Xs[xri][xc + 16]) = xv2;
    *reinterpret_cast<short8*>(&Xs[xri][xc + 24]) = xv3;
    *reinterpret_cast<short8*>(&Fs[fri][fc]) = fv0;
    *reinterpret_cast<short8*>(&Fs[fri][fc + 8]) = fv1;
    __syncthreads();
    int kn = k0 + 64;
    if (kn < K) {  // prefetch next tile; latency hides under MFMAs
      if (tokr >= 0) {
        xv0 = *reinterpret_cast<const short8*>(xrow + kn);
        xv1 = *reinterpret_cast<const short8*>(xrow + kn + 8);
        xv2 = *reinterpret_cast<const short8*>(xrow + kn + 16);
        xv3 = *reinterpret_cast<const short8*>(xrow + kn + 24);
      }
      fv0 = *reinterpret_cast<const short8*>(frow + kn);
      fv1 = *reinterpret_cast<const short8*>(frow + kn + 8);
    }
#pragma unroll
    for (int kk = 0; kk < 2; kk++) {
      short8 b0 = *reinterpret_cast<const short8*>(&Fs[wn * 32 + lr][kk * 32 + kg * 8]);
      short8 b1 = *reinterpret_cast<const short8*>(&Fs[wn * 32 + 16 + lr][kk * 32 + kg * 8]);
#pragma unroll
      for (int mi = 0; mi < 4; mi++) {
        short8 a = *reinterpret_cast<const short8*>(&Xs[wm * 64 + mi * 16 + lr][kk * 32 + kg * 8]);
        acc[mi][0] = __builtin_amdgcn_mfma_f32_16x16x32_bf16(a, b0, acc[mi][0], 0, 0, 0);
        acc[mi][1] = __builtin_amdgcn_mfma_f32_16x16x32_bf16(a, b1, acc[mi][1], 0, 0, 0);
      }
    }
  }
  int gbase = r * 4 * BS + offsb[gr * NEXP + e] + m0;
#pragma unroll
  for (int mi = 0; mi < 4; mi++) {
#pragma unroll
    for (int j = 0; j < 4; j++) {
      int row = wm * 64 + mi * 16 + kg * 4 + j;
      if (toks[row] < 0) continue;
      u16* crow = Cout + (size_t)(gbase + row) * NOUT + n0 + wn * 32;
#pragma unroll
      for (int ni = 0; ni < 2; ni++)
        crow[ni * 16 + lr] = bfbits(acc[mi][ni][j]);
    }
  }
}

// ------- batched gather: blockIdx.y = r; per-route slices at fixed strides -------
template <int NOUT, bool FINAL>
__global__ __launch_bounds__(256) void gather_combine(
    const u16* __restrict__ C,
    const float* __restrict__ w8base,
    const int* __restrict__ slotbase,
    const int* __restrict__ offsbase,
    const float* __restrict__ resid,
    float* __restrict__ outf,
    u16* __restrict__ outbase) {
  int tok = blockIdx.x;
  int r = blockIdx.y;
  const float* wr = w8base + (size_t)r * WSTR;
  const int* smap = slotbase + (size_t)r * LSTR;
  const int* offs = offsbase + r * NEXP;
  const u16* Cr = C + (size_t)r * 4 * BS * NOUT;
  int t = threadIdx.x;
  __shared__ float lw[4];
  __shared__ int ls[4];
  __shared__ int lcnt;
  if (t < 64) {
    float wv = (t < NEXP) ? wr[(size_t)tok * NEXP + t] : 0.f;
    bool act = wv != 0.f;
    unsigned long long mask = __ballot(act);
    int pos = __popcll(mask & ((1ull << t) - 1ull));
    if (act) { ls[pos] = offs[t] + smap[t * BS + tok]; lw[pos] = wv; }
    if (t == 0) lcnt = __popcll(mask);
  }
  __syncthreads();
  if (t < NOUT / 4) {
    float4 s = {0.f, 0.f, 0.f, 0.f};
    int cnt = lcnt;
    for (int k = 0; k < cnt; k++) {
      ushort4 v = reinterpret_cast<const ushort4*>(Cr + (size_t)ls[k] * NOUT)[t];
      float wk = lw[k];
      s.x += wk * b2f(v.x); s.y += wk * b2f(v.y);
      s.z += wk * b2f(v.z); s.w += wk * b2f(v.w);
    }
    if (FINAL) {
      float4 rr = reinterpret_cast<const float4*>(resid + (size_t)tok * NOUT)[t];
      s.x += rr.x; s.y += rr.y; s.z += rr.z; s.w += rr.w;
      reinterpret_cast<float4*>(outf + (size_t)tok * NOUT)[t] = s;
    } else {
      ushort4 o;
      o.x = bfbits(s.x); o.y = bfbits(s.y); o.z = bfbits(s.z); o.w = bfbits(s.w);
      reinterpret_cast<ushort4*>(outbase + (size_t)r * BS * NOUT + (size_t)tok * NOUT)[t] = o;
    }
  }
}

// ---------------- dense bf16 MFMA GEMM: C = A@B (+res), BT = B^T [N][K] ------
template <bool RES>
__global__ __launch_bounds__(256) void dense_gemm_mfma(
    const u16* __restrict__ Ab,
    const u16* __restrict__ BT,
    const float* __restrict__ res,
    float* __restrict__ C, int M, int N, int K) {
  int n0 = blockIdx.x * 64, m0 = blockIdx.y * 64;
  __shared__ u16 Xs[64][72];
  __shared__ u16 Fs[64][72];
  int t = threadIdx.x;
  int wave = t >> 6, lane = t & 63;
  int wm = wave >> 1, wn = wave & 1;
  int lr = lane & 15, kg = lane >> 4;
  f32x4 acc[2][2] = {};
  int srow = t >> 2, sc = (t & 3) * 16;
  const u16* xrow = Ab + (size_t)(m0 + srow) * K + sc;
  const u16* frow = BT + (size_t)(n0 + srow) * K + sc;
  for (int k0 = 0; k0 < K; k0 += 64) {
    short8 xv0 = *reinterpret_cast<const short8*>(xrow + k0);
    short8 xv1 = *reinterpret_cast<const short8*>(xrow + k0 + 8);
    short8 fv0 = *reinterpret_cast<const short8*>(frow + k0);
    short8 fv1 = *reinterpret_cast<const short8*>(frow + k0 + 8);
    __syncthreads();
    *reinterpret_cast<short8*>(&Xs[srow][sc]) = xv0;
    *reinterpret_cast<short8*>(&Xs[srow][sc + 8]) = xv1;
    *reinterpret_cast<short8*>(&Fs[srow][sc]) = fv0;
    *reinterpret_cast<short8*>(&Fs[srow][sc + 8]) = fv1;
    __syncthreads();
#pragma unroll
    for (int kk = 0; kk < 2; kk++) {
      short8 a0 = *reinterpret_cast<const short8*>(&Xs[wm * 32 + lr][kk * 32 + kg * 8]);
      short8 a1 = *reinterpret_cast<const short8*>(&Xs[wm * 32 + 16 + lr][kk * 32 + kg * 8]);
      short8 b0 = *reinterpret_cast<const short8*>(&Fs[wn * 32 + lr][kk * 32 + kg * 8]);
      short8 b1 = *reinterpret_cast<const short8*>(&Fs[wn * 32 + 16 + lr][kk * 32 + kg * 8]);
      acc[0][0] = __builtin_amdgcn_mfma_f32_16x16x32_bf16(a0, b0, acc[0][0], 0, 0, 0);
      acc[0][1] = __builtin_amdgcn_mfma_f32_16x16x32_bf16(a0, b1, acc[0][1], 0, 0, 0);
      acc[1][0] = __builtin_amdgcn_mfma_f32_16x16x32_bf16(a1, b0, acc[1][0], 0, 0, 0);
      acc[1][1] = __builtin_amdgcn_mfma_f32_16x16x32_bf16(a1, b1, acc[1][1], 0, 0, 0);
    }
  }
#pragma unroll
  for (int mi = 0; mi < 2; mi++) {
#pragma unroll
    for (int j = 0; j < 4; j++) {
      int row = m0 + wm * 32 + mi * 16 + kg * 4 + j;
#pragma unroll
      for (int ni = 0; ni < 2; ni++) {
        int col = n0 + wn * 32 + ni * 16 + lr;
        float v = acc[mi][ni][j];
        if (RES) v += res[(size_t)row * N + col];
        C[(size_t)row * N + col] = v;
      }
    }
  }
}

// ---------------- causal flash attention (bf16 MFMA, bf16 inputs) ----------------
__global__ __launch_bounds__(256) void attn_mfma(const u16* __restrict__ Qb,
                                                 const u16* __restrict__ Kb,
                                                 const u16* __restrict__ Vb,
                                                 u16* __restrict__ Ob) {
  int qt = (gridDim.x - 1 - blockIdx.x) * 64;  // long blocks first
  int h = blockIdx.y, b = blockIdx.z;
  int t = threadIdx.x;
  int w = t >> 6, lane = t & 63;
  int lr = lane & 15, kg = lane >> 4;
  __shared__ u16 Ks[64][72];
  __shared__ u16 Vs[64][66];
  __shared__ u16 Ps[4][16][72];
  size_t base = (size_t)(b * SEQ) * DMODEL + (size_t)h * DHEAD;
  const u16* qrow = Qb + base + (size_t)(qt + w * 16 + lr) * DMODEL + kg * 8;
  short8 aq0 = *reinterpret_cast<const short8*>(qrow);
  short8 aq1 = *reinterpret_cast<const short8*>(qrow + 32);
  float m[4], l[4];
#pragma unroll
  for (int j = 0; j < 4; j++) { m[j] = -1e30f; l[j] = 0.f; }
  f32x4 acc_o[4] = {};
  for (int kt = 0; kt <= qt; kt += 64) {
    __syncthreads();
    {
      int r = t >> 2, c0 = (t & 3) * 16;
      const u16* krow = Kb + base + (size_t)(kt + r) * DMODEL + c0;
      *reinterpret_cast<short8*>(&Ks[r][c0]) = *reinterpret_cast<const short8*>(krow);
      *reinterpret_cast<short8*>(&Ks[r][c0 + 8]) = *reinterpret_cast<const short8*>(krow + 8);
      int d = lane;
      int r0v = w * 16;
      const u16* vcol = Vb + base + (size_t)(kt + r0v) * DMODEL + d;
#pragma unroll
      for (int i = 0; i < 16; i++)
        Vs[d][r0v + i] = vcol[(size_t)i * DMODEL];
    }
    __syncthreads();
    f32x4 s[4] = {};
#pragma unroll
    for (int c = 0; c < 4; c++) {
      short8 bk0 = *reinterpret_cast<const short8*>(&Ks[c * 16 + lr][kg * 8]);
      short8 bk1 = *reinterpret_cast<const short8*>(&Ks[c * 16 + lr][32 + kg * 8]);
      s[c] = __builtin_amdgcn_mfma_f32_16x16x32_bf16(aq0, bk0, s[c], 0, 0, 0);
      s[c] = __builtin_amdgcn_mfma_f32_16x16x32_bf16(aq1, bk1, s[c], 0, 0, 0);
    }
#pragma unroll
    for (int c = 0; c < 4; c++)
#pragma unroll
      for (int j = 0; j < 4; j++) s[c][j] *= 0.125f;
    if (kt == qt) {
#pragma unroll
      for (int c = 0; c < 4; c++)
#pragma unroll
        for (int j = 0; j < 4; j++)
          if (c * 16 + lr > w * 16 + kg * 4 + j) s[c][j] = -1e30f;
    }
    float mt[4];
#pragma unroll
    for (int j = 0; j < 4; j++)
      mt[j] = fmaxf(fmaxf(s[0][j], s[1][j]), fmaxf(s[2][j], s[3][j]));
#pragma unroll
    for (int off = 1; off < 16; off <<= 1)
#pragma unroll
      for (int j = 0; j < 4; j++) mt[j] = fmaxf(mt[j], __shfl_xor(mt[j], off));
    float corr[4];
#pragma unroll
    for (int j = 0; j < 4; j++) {
      float mn = fmaxf(m[j], mt[j]);
      corr[j] = __expf(m[j] - mn);
      m[j] = mn;
      l[j] *= corr[j];
    }
#pragma unroll
    for (int di = 0; di < 4; di++)
#pragma unroll
      for (int j = 0; j < 4; j++) acc_o[di][j] *= corr[j];
    float ps[4] = {0.f, 0.f, 0.f, 0.f};
#pragma unroll
    for (int c = 0; c < 4; c++)
#pragma unroll
      for (int j = 0; j < 4; j++) {
        float p = __expf(s[c][j] - m[j]);
        ps[j] += p;
        s[c][j] = p;
      }
#pragma unroll
    for (int off = 1; off < 16; off <<= 1)
#pragma unroll
      for (int j = 0; j < 4; j++) ps[j] += __shfl_xor(ps[j], off);
#pragma unroll
    for (int j = 0; j < 4; j++) l[j] += ps[j];
#pragma unroll
    for (int c = 0; c < 4; c++)
#pragma unroll
      for (int j = 0; j < 4; j++)
        Ps[w][kg * 4 + j][c * 16 + lr] = bfbits(s[c][j]);
    short8 pa0 = *reinterpret_cast<const short8*>(&Ps[w][lr][kg * 8]);
    short8 pa1 = *reinterpret_cast<const short8*>(&Ps[w][lr][32 + kg * 8]);
#pragma unroll
    for (int di = 0; di < 4; di++) {
      short8 bv0 = *reinterpret_cast<const short8*>(&Vs[di * 16 + lr][kg * 8]);
      short8 bv1 = *reinterpret_cast<const short8*>(&Vs[di * 16 + lr][32 + kg * 8]);
      acc_o[di] = __builtin_amdgcn_mfma_f32_16x16x32_bf16(pa0, bv0, acc_o[di], 0, 0, 0);
      acc_o[di] = __builtin_amdgcn_mfma_f32_16x16x32_bf16(pa1, bv1, acc_o[di], 0, 0, 0);
    }
  }
#pragma unroll
  for (int j = 0; j < 4; j++) {
    float inv = 1.f / l[j];
    size_t rowoff = base + (size_t)(qt + w * 16 + kg * 4 + j) * DMODEL;
#pragma unroll
    for (int di = 0; di < 4; di++)
      Ob[rowoff + di * 16 + lr] = bfbits(acc_o[di][j] * inv);
  }
}

// ---------------- launch ----------------
extern "C" void kernel_launch(void* const* d_in, const int* in_sizes, int n_in,
                              void* d_out, int out_size, void* d_ws, size_t ws_size,
                              hipStream_t stream) {
  const float* x    = (const float*)d_in[0];
  const float* f_qk = (const float*)d_in[1];
  const float* f_v  = (const float*)d_in[2];
  const float* r_qk = (const float*)d_in[3];
  const float* r_v  = (const float*)d_in[4];
  const float* f_kn = (const float*)d_in[5];
  const float* r_kn = (const float*)d_in[6];
  const float* nemb = (const float*)d_in[7];
  const float* W_all = (const float*)d_in[8];
  const float* b_all = (const float*)d_in[9];
  const float* W_fk  = (const float*)d_in[10];
  const float* b_fk  = (const float*)d_in[11];
  const float* W_rk  = (const float*)d_in[12];
  const float* b_rk  = (const float*)d_in[13];
  const float* W_o   = (const float*)d_in[14];
  const float* ln1s  = (const float*)d_in[15];
  const float* ln1b  = (const float*)d_in[16];
  const float* ln2s  = (const float*)d_in[17];
  const float* ln2b  = (const float*)d_in[18];

  float* ws = (float*)d_ws;
  size_t off = 0;
  auto alloc = [&](size_t nf) { float* p = ws + off; off += nf; return p; };
  float* nx      = alloc((size_t)BS * DMODEL);
  float* nx2     = alloc((size_t)BS * DMODEL);
  float* embn    = alloc(6 * NEXP * DSP);
  float* h_all   = alloc((size_t)BS * HALL_N);
  float* hk2     = alloc((size_t)2 * BS * DSP);    // h_fk2 | h_rk2 contiguous
  float* w8      = alloc((size_t)8 * BS * NEXP);
  float* x1      = alloc((size_t)BS * DMODEL);
  float* compactFf = alloc((size_t)3 * 2 * BS * RANK);    // 3 routes x 8192 x 512 u16
  float* compactRf = alloc((size_t)3 * 2 * BS * DMODEL);  // 3 routes x 8192 x 1024 u16 (+partials)
  int* lists   = (int*)(ws + off); off += (size_t)8 * NEXP * BS;
  int* slotmap = (int*)(ws + off); off += (size_t)8 * NEXP * BS;
  int* counts  = (int*)(ws + off); off += 8 * NEXP;
  int* offsb   = (int*)(ws + off); off += 8 * NEXP;
  u16* nxb  = (u16*)(ws + off); off += (size_t)BS * DMODEL / 2;
  u16* fqb  = (u16*)(ws + off); off += (size_t)3 * BS * RANK / 2;  // fqb|fkb|fvb contiguous
  u16* fnb  = (u16*)(ws + off); off += (size_t)BS * RANK / 2;
  u16* Qbb  = (u16*)(ws + off); off += (size_t)3 * BS * DMODEL / 2; // Q|K|V contiguous
  u16* attnOb = (u16*)(ws + off); off += (size_t)BS * DMODEL / 2;
  u16* woT  = (u16*)(ws + off); off += (size_t)DMODEL * DMODEL / 2;
  u16* wbufF = (u16*)(ws + off); off += (size_t)3 * NEXP * DMODEL * RANK / 2; // f_qk|f_v|f_kn
  u16* wbufR = (u16*)(ws + off); off += (size_t)3 * NEXP * RANK * DMODEL / 2; // r_qk|r_v|r_kn
  u16* compactF = (u16*)compactFf;
  u16* compactR = (u16*)compactRf;
  u16* fkb = fqb + (size_t)BS * RANK;
  u16* fvb = fkb + (size_t)BS * RANK;
  u16* Kbb = Qbb + (size_t)BS * DMODEL;
  u16* Vbb = Kbb + (size_t)BS * DMODEL;
  float* h_fk2 = hk2;
  float* partA = compactRf;  // W_all partials: 4*BS*384 = 3.1M fl < 12.6M
  float* partK = compactRf;  // W_fk+W_rk partials: 16*BS*64 = 2.1M fl
  (void)fkb; (void)fvb; (void)Kbb; (void)Vbb;

  // ---- weights & norms (no deps): single merged wconv for all 7 weight tensors ----
  embnorm_kernel<<<6 * NEXP, DSP, 0, stream>>>(nemb, embn);
  wconv_all_kernel<<<24832, 256, 0, stream>>>(f_qk, f_v, f_kn, r_qk, r_v, r_kn,
                                              W_o, wbufF, wbufR, woT);

  // ---- attention circuit ----
  ln_kernel<<<BS, 256, 0, stream>>>(x, ln1s, ln1b, nx, nxb);
  gemm_splitk<<<dim3(HALL_N / 64, BS / 64, 4), 256, 0, stream>>>(
      nx, W_all, partA, BS, HALL_N, DMODEL, DMODEL / 4);
  reduce_bias_kernel<<<(BS * HALL_N / 4 + 255) / 256, 256, 0, stream>>>(
      partA, b_all, h_all, BS * HALL_N, HALL_N, 4);

  route_kernel<<<dim3(BS, 6), 64, 0, stream>>>(h_all, DSP, HALL_N, embn, 0, w8);
  bucket_kernel<<<dim3(NEXP, 6), 64, 0, stream>>>(w8, lists, slotmap, counts, 0);
  scan32_kernel<<<6, 64, 0, stream>>>(counts, offsb);

  // merged feature GEMM: routes 0,1,2 (slots f_qk,f_qk,f_v)
  expert_gemm_mfma<<<dim3(RANK / 64, 3 * NEXP, BS / 128), 256, 0, stream>>>(
      nxb, wbufF, lists, counts, offsb, compactF,
      0, 0, 0, 1, 0, DMODEL, RANK);
  gather_combine<RANK, false><<<dim3(BS, 3), 256, 0, stream>>>(
      compactF, w8, slotmap, offsb, nullptr, nullptr, fqb);

  // merged restore GEMM: routes 3,4,5 (slots r_qk,r_qk,r_v), X = fqb|fkb|fvb
  expert_gemm_mfma<<<dim3(DMODEL / 64, 3 * NEXP, BS / 128), 256, 0, stream>>>(
      fqb, wbufR, lists, counts, offsb, compactR,
      3, 0, 0, 1, (size_t)BS * RANK, RANK, DMODEL);
  gather_combine<DMODEL, false><<<dim3(BS, 3), 256, 0, stream>>>(
      compactR, w8 + 3 * WSTR, slotmap + 3 * LSTR, offsb + 3 * NEXP,
      nullptr, nullptr, Qbb);

  attn_mfma<<<dim3(SEQ / 64, NHEAD, BATCH), 256, 0, stream>>>(Qbb, Kbb, Vbb, attnOb);

  dense_gemm_mfma<true><<<dim3(DMODEL / 64, BS / 64), 256, 0, stream>>>(
      attnOb, woT, x, x1, BS, DMODEL, DMODEL);

  // ---- knowledge circuit ----
  ln_kernel<<<BS, 256, 0, stream>>>(x1, ln2s, ln2b, nx2, nxb);
  gemm_splitk2<<<dim3(1, BS / 64, 16), 256, 0, stream>>>(
      nx2, W_fk, W_rk, partK, BS, DSP, DMODEL, DMODEL / 8);
  reduce_bias2_kernel<<<dim3((BS * DSP / 4 + 255) / 256, 2), 256, 0, stream>>>(
      partK, b_fk, b_rk, h_fk2, BS * DSP, DSP, 8);
  route_kernel<<<dim3(BS, 2), 64, 0, stream>>>(h_fk2, (size_t)BS * DSP, DSP, embn, 6, w8);
  bucket_kernel<<<dim3(NEXP, 2), 64, 0, stream>>>(w8, lists, slotmap, counts, 6);
  scan32_kernel<<<2, 64, 0, stream>>>(counts + 6 * NEXP, offsb + 6 * NEXP);

  expert_gemm_mfma<<<dim3(RANK / 64, NEXP, BS / 128), 256, 0, stream>>>(
      nxb, wbufF, lists, counts, offsb, compactF,
      6, 2, 2, 2, 0, DMODEL, RANK);
  gather_combine<RANK, false><<<dim3(BS, 1), 256, 0, stream>>>(
      compactF, w8 + 6 * WSTR, slotmap + 6 * LSTR, offsb + 6 * NEXP,
      nullptr, nullptr, fnb);
  expert_gemm_mfma<<<dim3(DMODEL / 64, NEXP, BS / 128), 256, 0, stream>>>(
      fnb, wbufR, lists, counts, offsb, compactR,
      7, 2, 2, 2, 0, RANK, DMODEL);
  // d_out = x1 + restore(featN)
  gather_combine<DMODEL, true><<<dim3(BS, 1), 256, 0, stream>>>(
      compactR, w8 + 7 * WSTR, slotmap + 7 * LSTR, offsb + 7 * NEXP,
      x1, (float*)d_out, nullptr);
}

// Round 15
// 517.247 us; speedup vs baseline: 1.1393x; 1.0060x over previous
//
#include <hip/hip_runtime.h>
#include <hip/hip_bf16.h>
#include <cstdint>

#define BS     2048   // B*S tokens
#define DMODEL 1024
#define RANK   512
#define NEXP   32
#define DSP    64
#define NHEAD  16
#define DHEAD  64
#define SEQ    1024
#define BATCH  2
#define HALL_N 384    // 6*DSP
#define WSTR   ((size_t)BS * NEXP)
#define LSTR   ((size_t)NEXP * BS)

typedef unsigned short u16;
typedef unsigned int u32;
typedef __attribute__((ext_vector_type(8))) short short8;
typedef __attribute__((ext_vector_type(4))) float f32x4;

__device__ __forceinline__ u16 bfbits(float x) {
  __hip_bfloat16 h = __float2bfloat16(x);
  return __builtin_bit_cast(u16, h);
}
__device__ __forceinline__ float b2f(u16 u) {
  unsigned int x = (unsigned int)u << 16;
  return __builtin_bit_cast(float, x);
}

// ---------------- LayerNorm (token per block, 256 thr, float4), fp32 + bf16 out ----
__global__ void ln_kernel(const float* __restrict__ x,
                          const float* __restrict__ sc,
                          const float* __restrict__ bi,
                          float* __restrict__ out,
                          u16* __restrict__ outb) {
  int tok = blockIdx.x;
  int t = threadIdx.x; // 256
  const float4* xr = reinterpret_cast<const float4*>(x + (size_t)tok * DMODEL);
  float4 v = xr[t];
  float s = v.x + v.y + v.z + v.w;
  float q = v.x * v.x + v.y * v.y + v.z * v.z + v.w * v.w;
#pragma unroll
  for (int off = 32; off > 0; off >>= 1) {
    s += __shfl_xor(s, off);
    q += __shfl_xor(q, off);
  }
  __shared__ float red[8];
  int wid = t >> 6;
  if ((t & 63) == 0) { red[wid] = s; red[4 + wid] = q; }
  __syncthreads();
  s = red[0] + red[1] + red[2] + red[3];
  q = red[4] + red[5] + red[6] + red[7];
  float mu = s * (1.f / DMODEL);
  float var = q * (1.f / DMODEL) - mu * mu;
  float inv = rsqrtf(var + 1e-6f);
  float4 scv = reinterpret_cast<const float4*>(sc)[t];
  float4 biv = reinterpret_cast<const float4*>(bi)[t];
  float4 r;
  r.x = (v.x - mu) * inv * scv.x + biv.x;
  r.y = (v.y - mu) * inv * scv.y + biv.y;
  r.z = (v.z - mu) * inv * scv.z + biv.z;
  r.w = (v.w - mu) * inv * scv.w + biv.w;
  reinterpret_cast<float4*>(out + (size_t)tok * DMODEL)[t] = r;
  ushort4 ob;
  ob.x = bfbits(r.x); ob.y = bfbits(r.y); ob.z = bfbits(r.z); ob.w = bfbits(r.w);
  reinterpret_cast<ushort4*>(outb + (size_t)tok * DMODEL)[t] = ob;
}

// ---------------- emb row L2-normalize ----------------
__global__ void embnorm_kernel(const float* __restrict__ e, float* __restrict__ o) {
  int row = blockIdx.x;
  int lane = threadIdx.x; // 64
  float v = e[row * DSP + lane];
  float q = v * v;
#pragma unroll
  for (int off = 32; off > 0; off >>= 1) q += __shfl_xor(q, off);
  o[row * DSP + lane] = v / (sqrtf(q) + 1e-8f);
}

// ---------------- fp32 split-K GEMM: part[ks] = A[M,Kc]@B[Kc,N] ----------------
__global__ __launch_bounds__(256) void gemm_splitk(const float* __restrict__ A,
                                                   const float* __restrict__ Bm,
                                                   float* __restrict__ part,
                                                   int M, int N, int K, int kchunk) {
  __shared__ float As[16][65];
  __shared__ float Bs[16][64];
  int n0 = blockIdx.x * 64;
  int m0 = blockIdx.y * 64;
  int kbeg = blockIdx.z * kchunk;
  int t = threadIdx.x;
  int tx = t & 15, ty = t >> 4;
  float c[4][4] = {};
  for (int k0 = kbeg; k0 < kbeg + kchunk; k0 += 16) {
#pragma unroll
    for (int i = 0; i < 4; i++) {
      int idx = t + i * 256;
      int m = idx >> 4, kk = idx & 15;
      As[kk][m] = A[(size_t)(m0 + m) * K + k0 + kk];
    }
#pragma unroll
    for (int i = 0; i < 4; i++) {
      int idx = t + i * 256;
      int kk = idx >> 6, nn = idx & 63;
      Bs[kk][nn] = Bm[(size_t)(k0 + kk) * N + n0 + nn];
    }
    __syncthreads();
#pragma unroll
    for (int kk = 0; kk < 16; kk++) {
      float a[4], b[4];
#pragma unroll
      for (int i = 0; i < 4; i++) a[i] = As[kk][ty + i * 16];
#pragma unroll
      for (int j = 0; j < 4; j++) b[j] = Bs[kk][tx + j * 16];
#pragma unroll
      for (int i = 0; i < 4; i++)
#pragma unroll
        for (int j = 0; j < 4; j++) c[i][j] += a[i] * b[j];
    }
    __syncthreads();
  }
  float* po = part + (size_t)blockIdx.z * M * N;
#pragma unroll
  for (int i = 0; i < 4; i++)
#pragma unroll
    for (int j = 0; j < 4; j++)
      po[(size_t)(m0 + ty + i * 16) * N + n0 + tx + j * 16] = c[i][j];
}

// ---------------- batched split-K for W_fk+W_rk (z = wsel*8 + ks) ----------------
__global__ __launch_bounds__(256) void gemm_splitk2(const float* __restrict__ A,
                                                    const float* __restrict__ B0,
                                                    const float* __restrict__ B1,
                                                    float* __restrict__ part,
                                                    int M, int N, int K, int kchunk) {
  __shared__ float As[16][65];
  __shared__ float Bs[16][64];
  int wsel = blockIdx.z >> 3, ks = blockIdx.z & 7;
  const float* Bm = wsel ? B1 : B0;
  int n0 = blockIdx.x * 64;
  int m0 = blockIdx.y * 64;
  int kbeg = ks * kchunk;
  int t = threadIdx.x;
  int tx = t & 15, ty = t >> 4;
  float c[4][4] = {};
  for (int k0 = kbeg; k0 < kbeg + kchunk; k0 += 16) {
#pragma unroll
    for (int i = 0; i < 4; i++) {
      int idx = t + i * 256;
      int m = idx >> 4, kk = idx & 15;
      As[kk][m] = A[(size_t)(m0 + m) * K + k0 + kk];
    }
#pragma unroll
    for (int i = 0; i < 4; i++) {
      int idx = t + i * 256;
      int kk = idx >> 6, nn = idx & 63;
      Bs[kk][nn] = Bm[(size_t)(k0 + kk) * N + n0 + nn];
    }
    __syncthreads();
#pragma unroll
    for (int kk = 0; kk < 16; kk++) {
      float a[4], b[4];
#pragma unroll
      for (int i = 0; i < 4; i++) a[i] = As[kk][ty + i * 16];
#pragma unroll
      for (int j = 0; j < 4; j++) b[j] = Bs[kk][tx + j * 16];
#pragma unroll
      for (int i = 0; i < 4; i++)
#pragma unroll
        for (int j = 0; j < 4; j++) c[i][j] += a[i] * b[j];
    }
    __syncthreads();
  }
  float* po = part + (size_t)blockIdx.z * M * N;
#pragma unroll
  for (int i = 0; i < 4; i++)
#pragma unroll
    for (int j = 0; j < 4; j++)
      po[(size_t)(m0 + ty + i * 16) * N + n0 + tx + j * 16] = c[i][j];
}

// ---------------- split-K reduce + bias ----------------
__global__ void reduce_bias_kernel(const float* __restrict__ part,
                                   const float* __restrict__ bias,
                                   float* __restrict__ out,
                                   int MN, int N, int KS) {
  int i = blockIdx.x * 256 + threadIdx.x;
  if (i * 4 >= MN) return;
  float4 s = reinterpret_cast<const float4*>(part)[i];
  for (int ks = 1; ks < KS; ks++) {
    float4 p = reinterpret_cast<const float4*>(part + (size_t)ks * MN)[i];
    s.x += p.x; s.y += p.y; s.z += p.z; s.w += p.w;
  }
  int col = (i * 4) % N;
  float4 b = *reinterpret_cast<const float4*>(bias + col);
  s.x += b.x; s.y += b.y; s.z += b.z; s.w += b.w;
  reinterpret_cast<float4*>(out)[i] = s;
}

// ---------------- batched reduce for W_fk/W_rk (blockIdx.y = wsel) ----------------
__global__ void reduce_bias2_kernel(const float* __restrict__ part,
                                    const float* __restrict__ bias0,
                                    const float* __restrict__ bias1,
                                    float* __restrict__ out,
                                    int MN, int N, int KS) {
  int wsel = blockIdx.y;
  const float* p0 = part + (size_t)wsel * KS * MN;
  const float* bias = wsel ? bias1 : bias0;
  float* o = out + (size_t)wsel * MN;
  int i = blockIdx.x * 256 + threadIdx.x;
  if (i * 4 >= MN) return;
  float4 s = reinterpret_cast<const float4*>(p0)[i];
  for (int ks = 1; ks < KS; ks++) {
    float4 p = reinterpret_cast<const float4*>(p0 + (size_t)ks * MN)[i];
    s.x += p.x; s.y += p.y; s.z += p.z; s.w += p.w;
  }
  int col = (i * 4) % N;
  float4 b = *reinterpret_cast<const float4*>(bias + col);
  s.x += b.x; s.y += b.y; s.z += b.z; s.w += b.w;
  reinterpret_cast<float4*>(o)[i] = s;
}

// ------- batched routing: blockIdx.y = r, global route = R0 + r -------
__global__ void route_kernel(const float* __restrict__ h, size_t roff, int ldh,
                             const float* __restrict__ embn, int R0,
                             float* __restrict__ w8) {
  int tok = blockIdx.x;
  int r = blockIdx.y;
  int gr = R0 + r;
  int pool = (gr < 2) ? 0 : (gr < 3) ? 1 : (gr < 5) ? 2 : (gr < 6) ? 3 : (gr < 7) ? 4 : 5;
  const float* e = embn + (size_t)pool * NEXP * DSP;
  const float* hr = h + (size_t)r * roff;
  float* wout = w8 + (size_t)gr * WSTR;
  int lane = threadIdx.x; // 64
  __shared__ float hs[DSP];
  __shared__ float es[NEXP * DSP];
  hs[lane] = hr[(size_t)tok * ldh + lane];
#pragma unroll
  for (int i = 0; i < NEXP * DSP / 64; i++) es[lane + i * 64] = e[lane + i * 64];
  __syncthreads();
  float logit = -1e30f;
  if (lane < NEXP) {
    float s = 0.f;
#pragma unroll
    for (int d = 0; d < DSP; d++) s += hs[d] * es[lane * DSP + d];
    logit = s;
  }
  float mx = logit;
#pragma unroll
  for (int off = 16; off > 0; off >>= 1) mx = fmaxf(mx, __shfl_xor(mx, off));
  float p = (lane < NEXP) ? __expf(logit - mx) : 0.f;
  float sum = p;
#pragma unroll
  for (int off = 16; off > 0; off >>= 1) sum += __shfl_xor(sum, off);
  p = p / sum;
  float val = p;
  float chosen = 0.f;
  float selsum = 0.f;
#pragma unroll
  for (int it = 0; it < 4; it++) {
    float v = val;
    int vi = lane;
#pragma unroll
    for (int off = 16; off > 0; off >>= 1) {
      float ov = __shfl_xor(v, off);
      int oi = __shfl_xor(vi, off);
      if (ov > v || (ov == v && oi < vi)) { v = ov; vi = oi; }
    }
    if (lane == vi) { chosen = p; val = -1.f; }
    selsum += v;
  }
  if (lane < NEXP) wout[(size_t)tok * NEXP + lane] = chosen / (selsum + 1e-8f);
}

// ------- batched bucket: blockIdx.y = r (global route R0 + r) -------
__global__ void bucket_kernel(const float* __restrict__ w8,
                              int* __restrict__ lists,
                              int* __restrict__ slotmap,
                              int* __restrict__ counts, int R0) {
  int n = blockIdx.x;
  int gr = R0 + blockIdx.y;
  const float* w = w8 + (size_t)gr * WSTR;
  int* list = lists + (size_t)gr * LSTR;
  int* smap = slotmap + (size_t)gr * LSTR;
  int lane = threadIdx.x; // 64
  int base = 0;
  for (int t0 = 0; t0 < BS; t0 += 64) {
    int tok = t0 + lane;
    bool act = (w[(size_t)tok * NEXP + n] != 0.f);
    unsigned long long mask = __ballot(act);
    int pos = __popcll(mask & ((1ull << lane) - 1ull));
    if (act) {
      list[n * BS + base + pos] = tok;
      smap[n * BS + tok] = base + pos;
    }
    base += __popcll(mask);
  }
  if (lane == 0) counts[gr * NEXP + n] = base;
}

// ---------------- exclusive scan of 32 counts per route ----------------
__global__ void scan32_kernel(const int* __restrict__ counts, int* __restrict__ offs) {
  int r = blockIdx.x;
  int lane = threadIdx.x; // 64
  int c = (lane < NEXP) ? counts[r * NEXP + lane] : 0;
  int s = c;
#pragma unroll
  for (int d = 1; d < NEXP; d <<= 1) {
    int o = __shfl_up(s, d);
    if (lane >= d) s += o;
  }
  if (lane < NEXP) offs[r * NEXP + lane] = s - c;
}

// ---- conflict-free wconv, 64n x 128k tile (256B contiguous on BOTH global sides).
// 512 thr, LDS [64][130] u16 (pitch 65 dwords == 1 mod 32), per-row XOR key
// ((row>>2)&7)<<4 (chunk-aligned, bijective). Blocks: 0..6143 features
// (K=1024,NOUT=512, 8n x 8k per expert); 6144..12287 restores (K=512,NOUT=1024,
// 16n x 4k); 12288..12415 W_o (16n x 8k).
#define KSWZ(row, k) ((k) ^ ((((row) >> 2) & 7) << 4))
__global__ __launch_bounds__(512) void wconv_all_kernel(
    const float* __restrict__ F0, const float* __restrict__ F1,
    const float* __restrict__ F2,
    const float* __restrict__ R0w, const float* __restrict__ R1w,
    const float* __restrict__ R2w,
    const float* __restrict__ W_o,
    u16* __restrict__ wbufF, u16* __restrict__ wbufR, u16* __restrict__ woT) {
  __shared__ u16 tile[64][130];
  int bid = blockIdx.x;
  const float* Fe;
  u16* FTe;
  int K, NOUT, n0, k0;
  if (bid < 6144) {
    K = DMODEL; NOUT = RANK;
    n0 = (bid & 7) * 64; k0 = ((bid >> 3) & 7) * 128;
    int z = bid >> 6;
    int p = z >> 5, e = z & 31;
    Fe = ((p == 0) ? F0 : (p == 1) ? F1 : F2) + (size_t)e * K * NOUT;
    FTe = wbufF + (size_t)z * K * NOUT;
  } else if (bid < 12288) {
    int wbid = bid - 6144;
    K = RANK; NOUT = DMODEL;
    n0 = (wbid & 15) * 64; k0 = ((wbid >> 4) & 3) * 128;
    int z = wbid >> 6;
    int p = z >> 5, e = z & 31;
    Fe = ((p == 0) ? R0w : (p == 1) ? R1w : R2w) + (size_t)e * K * NOUT;
    FTe = wbufR + (size_t)z * K * NOUT;
  } else {
    int wbid = bid - 12288;
    K = DMODEL; NOUT = DMODEL;
    n0 = (wbid & 15) * 64; k0 = (wbid >> 4) * 128;
    Fe = W_o; FTe = woT;
  }
  int t = threadIdx.x;
  int kr = t >> 4, nc = (t & 15) * 4;  // 32 k-rows/pass x 16 float4
#pragma unroll
  for (int p = 0; p < 4; p++) {
    int kk = kr + p * 32;
    float4 v = *reinterpret_cast<const float4*>(Fe + (size_t)(k0 + kk) * NOUT + n0 + nc);
    tile[nc + 0][KSWZ(nc + 0, kk)] = bfbits(v.x);
    tile[nc + 1][KSWZ(nc + 1, kk)] = bfbits(v.y);
    tile[nc + 2][KSWZ(nc + 2, kk)] = bfbits(v.z);
    tile[nc + 3][KSWZ(nc + 3, kk)] = bfbits(v.w);
  }
  __syncthreads();
  int nr = t >> 3, cb = (t & 7) * 16;  // 64 rows, 8 thr/row, 32B each
  int srcbase = KSWZ(nr, cb) >> 1;     // chunk-aligned: maps 16-u16 chunk
  const u32* rowp = reinterpret_cast<const u32*>(&tile[nr][0]);
  u32 u[8];
#pragma unroll
  for (int s = 0; s < 8; s++) u[s] = rowp[srcbase + s];
  u16* dst = FTe + (size_t)(n0 + nr) * K + k0 + cb;
  *reinterpret_cast<uint4*>(dst) = *reinterpret_cast<uint4*>(&u[0]);
  *reinterpret_cast<uint4*>(dst + 8) = *reinterpret_cast<uint4*>(&u[4]);
}

// ---------------- merged expert GEMM (bf16 MFMA, 128x64, multi-route) ----------------
__global__ __launch_bounds__(256) void expert_gemm_mfma(
    const u16* __restrict__ Xb,     // bf16 activations (base)
    const u16* __restrict__ FT,     // [pools*32][NOUT][K] bf16
    const int* __restrict__ lists,  // [8][32][BS]
    const int* __restrict__ counts, // [8][32]
    const int* __restrict__ offsb,  // [8][32]
    u16* __restrict__ Cout,         // compact bf16, + r*4*BS rows
    int R0, int s0, int s1, int s2,
    size_t xstride, int K, int NOUT) {
  int v = blockIdx.y;
  int r = v >> 5, e = v & 31;
  int gr = R0 + r;
  int cnt = counts[gr * NEXP + e];
  int m0 = blockIdx.z * 128;
  if (m0 >= cnt) return;
  int slot = (r == 0) ? s0 : (r == 1) ? s1 : s2;
  int n0 = blockIdx.x * 64;
  const int* list = lists + (size_t)gr * LSTR + (size_t)e * BS;
  __shared__ u16 Xs[128][72];
  __shared__ u16 Fs[64][72];
  __shared__ int toks[128];
  int t = threadIdx.x;
  if (t < 128) toks[t] = (m0 + t < cnt) ? list[m0 + t] : -1;
  __syncthreads();
  const u16* X = Xb + (size_t)r * xstride;
  const u16* FTe = FT + ((size_t)(slot * NEXP + e) * NOUT + n0) * K;
  int wave = t >> 6, lane = t & 63;
  int wm = wave >> 1, wn = wave & 1;
  int lr = lane & 15, kg = lane >> 4;
  f32x4 acc[4][2] = {};
  int xri = t >> 1, xc = (t & 1) * 32;
  int tokr = toks[xri];
  const u16* xrow = X + (size_t)(tokr < 0 ? 0 : tokr) * K + xc;
  int fri = t >> 2, fc = (t & 3) * 16;
  const u16* frow = FTe + (size_t)fri * K + fc;
  short8 xv0 = {}, xv1 = {}, xv2 = {}, xv3 = {}, fv0, fv1;
  if (tokr >= 0) {
    xv0 = *reinterpret_cast<const short8*>(xrow);
    xv1 = *reinterpret_cast<const short8*>(xrow + 8);
    xv2 = *reinterpret_cast<const short8*>(xrow + 16);
    xv3 = *reinterpret_cast<const short8*>(xrow + 24);
  }
  fv0 = *reinterpret_cast<const short8*>(frow);
  fv1 = *reinterpret_cast<const short8*>(frow + 8);
  for (int k0 = 0; k0 < K; k0 += 64) {
    __syncthreads();
    *reinterpret_cast<short8*>(&Xs[xri][xc]) = xv0;
    *reinterpret_cast<short8*>(&Xs[xri][xc + 8]) = xv1;
    *reinterpret_cast<short8*>(&Xs[xri][xc + 16]) = xv2;
    *reinterpret_cast<short8*>(&Xs[xri][xc + 24]) = xv3;
    *reinterpret_cast<short8*>(&Fs[fri][fc]) = fv0;
    *reinterpret_cast<short8*>(&Fs[fri][fc + 8]) = fv1;
    __syncthreads();
    int kn = k0 + 64;
    if (kn < K) {  // prefetch next tile; latency hides under MFMAs
      if (tokr >= 0) {
        xv0 = *reinterpret_cast<const short8*>(xrow + kn);
        xv1 = *reinterpret_cast<const short8*>(xrow + kn + 8);
        xv2 = *reinterpret_cast<const short8*>(xrow + kn + 16);
        xv3 = *reinterpret_cast<const short8*>(xrow + kn + 24);
      }
      fv0 = *reinterpret_cast<const short8*>(frow + kn);
      fv1 = *reinterpret_cast<const short8*>(frow + kn + 8);
    }
#pragma unroll
    for (int kk = 0; kk < 2; kk++) {
      short8 b0 = *reinterpret_cast<const short8*>(&Fs[wn * 32 + lr][kk * 32 + kg * 8]);
      short8 b1 = *reinterpret_cast<const short8*>(&Fs[wn * 32 + 16 + lr][kk * 32 + kg * 8]);
#pragma unroll
      for (int mi = 0; mi < 4; mi++) {
        short8 a = *reinterpret_cast<const short8*>(&Xs[wm * 64 + mi * 16 + lr][kk * 32 + kg * 8]);
        acc[mi][0] = __builtin_amdgcn_mfma_f32_16x16x32_bf16(a, b0, acc[mi][0], 0, 0, 0);
        acc[mi][1] = __builtin_amdgcn_mfma_f32_16x16x32_bf16(a, b1, acc[mi][1], 0, 0, 0);
      }
    }
  }
  int gbase = r * 4 * BS + offsb[gr * NEXP + e] + m0;
#pragma unroll
  for (int mi = 0; mi < 4; mi++) {
#pragma unroll
    for (int j = 0; j < 4; j++) {
      int row = wm * 64 + mi * 16 + kg * 4 + j;
      if (toks[row] < 0) continue;
      u16* crow = Cout + (size_t)(gbase + row) * NOUT + n0 + wn * 32;
#pragma unroll
      for (int ni = 0; ni < 2; ni++)
        crow[ni * 16 + lr] = bfbits(acc[mi][ni][j]);
    }
  }
}

// ------- batched gather: blockIdx.y = r; per-route slices at fixed strides -------
template <int NOUT, bool FINAL>
__global__ __launch_bounds__(256) void gather_combine(
    const u16* __restrict__ C,
    const float* __restrict__ w8base,
    const int* __restrict__ slotbase,
    const int* __restrict__ offsbase,
    const float* __restrict__ resid,
    float* __restrict__ outf,
    u16* __restrict__ outbase) {
  int tok = blockIdx.x;
  int r = blockIdx.y;
  const float* wr = w8base + (size_t)r * WSTR;
  const int* smap = slotbase + (size_t)r * LSTR;
  const int* offs = offsbase + r * NEXP;
  const u16* Cr = C + (size_t)r * 4 * BS * NOUT;
  int t = threadIdx.x;
  __shared__ float lw[4];
  __shared__ int ls[4];
  __shared__ int lcnt;
  if (t < 64) {
    float wv = (t < NEXP) ? wr[(size_t)tok * NEXP + t] : 0.f;
    bool act = wv != 0.f;
    unsigned long long mask = __ballot(act);
    int pos = __popcll(mask & ((1ull << t) - 1ull));
    if (act) { ls[pos] = offs[t] + smap[t * BS + tok]; lw[pos] = wv; }
    if (t == 0) lcnt = __popcll(mask);
  }
  __syncthreads();
  if (t < NOUT / 4) {
    float4 s = {0.f, 0.f, 0.f, 0.f};
    int cnt = lcnt;
    for (int k = 0; k < cnt; k++) {
      ushort4 v = reinterpret_cast<const ushort4*>(Cr + (size_t)ls[k] * NOUT)[t];
      float wk = lw[k];
      s.x += wk * b2f(v.x); s.y += wk * b2f(v.y);
      s.z += wk * b2f(v.z); s.w += wk * b2f(v.w);
    }
    if (FINAL) {
      float4 rr = reinterpret_cast<const float4*>(resid + (size_t)tok * NOUT)[t];
      s.x += rr.x; s.y += rr.y; s.z += rr.z; s.w += rr.w;
      reinterpret_cast<float4*>(outf + (size_t)tok * NOUT)[t] = s;
    } else {
      ushort4 o;
      o.x = bfbits(s.x); o.y = bfbits(s.y); o.z = bfbits(s.z); o.w = bfbits(s.w);
      reinterpret_cast<ushort4*>(outbase + (size_t)r * BS * NOUT + (size_t)tok * NOUT)[t] = o;
    }
  }
}

// ---------------- dense bf16 MFMA GEMM: C = A@B (+res), BT = B^T [N][K] ------
template <bool RES>
__global__ __launch_bounds__(256) void dense_gemm_mfma(
    const u16* __restrict__ Ab,
    const u16* __restrict__ BT,
    const float* __restrict__ res,
    float* __restrict__ C, int M, int N, int K) {
  int n0 = blockIdx.x * 64, m0 = blockIdx.y * 64;
  __shared__ u16 Xs[64][72];
  __shared__ u16 Fs[64][72];
  int t = threadIdx.x;
  int wave = t >> 6, lane = t & 63;
  int wm = wave >> 1, wn = wave & 1;
  int lr = lane & 15, kg = lane >> 4;
  f32x4 acc[2][2] = {};
  int srow = t >> 2, sc = (t & 3) * 16;
  const u16* xrow = Ab + (size_t)(m0 + srow) * K + sc;
  const u16* frow = BT + (size_t)(n0 + srow) * K + sc;
  for (int k0 = 0; k0 < K; k0 += 64) {
    short8 xv0 = *reinterpret_cast<const short8*>(xrow + k0);
    short8 xv1 = *reinterpret_cast<const short8*>(xrow + k0 + 8);
    short8 fv0 = *reinterpret_cast<const short8*>(frow + k0);
    short8 fv1 = *reinterpret_cast<const short8*>(frow + k0 + 8);
    __syncthreads();
    *reinterpret_cast<short8*>(&Xs[srow][sc]) = xv0;
    *reinterpret_cast<short8*>(&Xs[srow][sc + 8]) = xv1;
    *reinterpret_cast<short8*>(&Fs[srow][sc]) = fv0;
    *reinterpret_cast<short8*>(&Fs[srow][sc + 8]) = fv1;
    __syncthreads();
#pragma unroll
    for (int kk = 0; kk < 2; kk++) {
      short8 a0 = *reinterpret_cast<const short8*>(&Xs[wm * 32 + lr][kk * 32 + kg * 8]);
      short8 a1 = *reinterpret_cast<const short8*>(&Xs[wm * 32 + 16 + lr][kk * 32 + kg * 8]);
      short8 b0 = *reinterpret_cast<const short8*>(&Fs[wn * 32 + lr][kk * 32 + kg * 8]);
      short8 b1 = *reinterpret_cast<const short8*>(&Fs[wn * 32 + 16 + lr][kk * 32 + kg * 8]);
      acc[0][0] = __builtin_amdgcn_mfma_f32_16x16x32_bf16(a0, b0, acc[0][0], 0, 0, 0);
      acc[0][1] = __builtin_amdgcn_mfma_f32_16x16x32_bf16(a0, b1, acc[0][1], 0, 0, 0);
      acc[1][0] = __builtin_amdgcn_mfma_f32_16x16x32_bf16(a1, b0, acc[1][0], 0, 0, 0);
      acc[1][1] = __builtin_amdgcn_mfma_f32_16x16x32_bf16(a1, b1, acc[1][1], 0, 0, 0);
    }
  }
#pragma unroll
  for (int mi = 0; mi < 2; mi++) {
#pragma unroll
    for (int j = 0; j < 4; j++) {
      int row = m0 + wm * 32 + mi * 16 + kg * 4 + j;
#pragma unroll
      for (int ni = 0; ni < 2; ni++) {
        int col = n0 + wn * 32 + ni * 16 + lr;
        float v = acc[mi][ni][j];
        if (RES) v += res[(size_t)row * N + col];
        C[(size_t)row * N + col] = v;
      }
    }
  }
}

// ---------------- causal flash attention (bf16 MFMA, bf16 inputs) ----------------
__global__ __launch_bounds__(256) void attn_mfma(const u16* __restrict__ Qb,
                                                 const u16* __restrict__ Kb,
                                                 const u16* __restrict__ Vb,
                                                 u16* __restrict__ Ob) {
  int qt = (gridDim.x - 1 - blockIdx.x) * 64;  // long blocks first
  int h = blockIdx.y, b = blockIdx.z;
  int t = threadIdx.x;
  int w = t >> 6, lane = t & 63;
  int lr = lane & 15, kg = lane >> 4;
  __shared__ u16 Ks[64][72];
  __shared__ u16 Vs[64][66];
  __shared__ u16 Ps[4][16][72];
  size_t base = (size_t)(b * SEQ) * DMODEL + (size_t)h * DHEAD;
  const u16* qrow = Qb + base + (size_t)(qt + w * 16 + lr) * DMODEL + kg * 8;
  short8 aq0 = *reinterpret_cast<const short8*>(qrow);
  short8 aq1 = *reinterpret_cast<const short8*>(qrow + 32);
  float m[4], l[4];
#pragma unroll
  for (int j = 0; j < 4; j++) { m[j] = -1e30f; l[j] = 0.f; }
  f32x4 acc_o[4] = {};
  for (int kt = 0; kt <= qt; kt += 64) {
    __syncthreads();
    {
      int r = t >> 2, c0 = (t & 3) * 16;
      const u16* krow = Kb + base + (size_t)(kt + r) * DMODEL + c0;
      *reinterpret_cast<short8*>(&Ks[r][c0]) = *reinterpret_cast<const short8*>(krow);
      *reinterpret_cast<short8*>(&Ks[r][c0 + 8]) = *reinterpret_cast<const short8*>(krow + 8);
      int d = lane;
      int r0v = w * 16;
      const u16* vcol = Vb + base + (size_t)(kt + r0v) * DMODEL + d;
#pragma unroll
      for (int i = 0; i < 16; i++)
        Vs[d][r0v + i] = vcol[(size_t)i * DMODEL];
    }
    __syncthreads();
    f32x4 s[4] = {};
#pragma unroll
    for (int c = 0; c < 4; c++) {
      short8 bk0 = *reinterpret_cast<const short8*>(&Ks[c * 16 + lr][kg * 8]);
      short8 bk1 = *reinterpret_cast<const short8*>(&Ks[c * 16 + lr][32 + kg * 8]);
      s[c] = __builtin_amdgcn_mfma_f32_16x16x32_bf16(aq0, bk0, s[c], 0, 0, 0);
      s[c] = __builtin_amdgcn_mfma_f32_16x16x32_bf16(aq1, bk1, s[c], 0, 0, 0);
    }
#pragma unroll
    for (int c = 0; c < 4; c++)
#pragma unroll
      for (int j = 0; j < 4; j++) s[c][j] *= 0.125f;
    if (kt == qt) {
#pragma unroll
      for (int c = 0; c < 4; c++)
#pragma unroll
        for (int j = 0; j < 4; j++)
          if (c * 16 + lr > w * 16 + kg * 4 + j) s[c][j] = -1e30f;
    }
    float mt[4];
#pragma unroll
    for (int j = 0; j < 4; j++)
      mt[j] = fmaxf(fmaxf(s[0][j], s[1][j]), fmaxf(s[2][j], s[3][j]));
#pragma unroll
    for (int off = 1; off < 16; off <<= 1)
#pragma unroll
      for (int j = 0; j < 4; j++) mt[j] = fmaxf(mt[j], __shfl_xor(mt[j], off));
    float corr[4];
#pragma unroll
    for (int j = 0; j < 4; j++) {
      float mn = fmaxf(m[j], mt[j]);
      corr[j] = __expf(m[j] - mn);
      m[j] = mn;
      l[j] *= corr[j];
    }
#pragma unroll
    for (int di = 0; di < 4; di++)
#pragma unroll
      for (int j = 0; j < 4; j++) acc_o[di][j] *= corr[j];
    float ps[4] = {0.f, 0.f, 0.f, 0.f};
#pragma unroll
    for (int c = 0; c < 4; c++)
#pragma unroll
      for (int j = 0; j < 4; j++) {
        float p = __expf(s[c][j] - m[j]);
        ps[j] += p;
        s[c][j] = p;
      }
#pragma unroll
    for (int off = 1; off < 16; off <<= 1)
#pragma unroll
      for (int j = 0; j < 4; j++) ps[j] += __shfl_xor(ps[j], off);
#pragma unroll
    for (int j = 0; j < 4; j++) l[j] += ps[j];
#pragma unroll
    for (int c = 0; c < 4; c++)
#pragma unroll
      for (int j = 0; j < 4; j++)
        Ps[w][kg * 4 + j][c * 16 + lr] = bfbits(s[c][j]);
    short8 pa0 = *reinterpret_cast<const short8*>(&Ps[w][lr][kg * 8]);
    short8 pa1 = *reinterpret_cast<const short8*>(&Ps[w][lr][32 + kg * 8]);
#pragma unroll
    for (int di = 0; di < 4; di++) {
      short8 bv0 = *reinterpret_cast<const short8*>(&Vs[di * 16 + lr][kg * 8]);
      short8 bv1 = *reinterpret_cast<const short8*>(&Vs[di * 16 + lr][32 + kg * 8]);
      acc_o[di] = __builtin_amdgcn_mfma_f32_16x16x32_bf16(pa0, bv0, acc_o[di], 0, 0, 0);
      acc_o[di] = __builtin_amdgcn_mfma_f32_16x16x32_bf16(pa1, bv1, acc_o[di], 0, 0, 0);
    }
  }
#pragma unroll
  for (int j = 0; j < 4; j++) {
    float inv = 1.f / l[j];
    size_t rowoff = base + (size_t)(qt + w * 16 + kg * 4 + j) * DMODEL;
#pragma unroll
    for (int di = 0; di < 4; di++)
      Ob[rowoff + di * 16 + lr] = bfbits(acc_o[di][j] * inv);
  }
}

// ---------------- launch ----------------
extern "C" void kernel_launch(void* const* d_in, const int* in_sizes, int n_in,
                              void* d_out, int out_size, void* d_ws, size_t ws_size,
                              hipStream_t stream) {
  const float* x    = (const float*)d_in[0];
  const float* f_qk = (const float*)d_in[1];
  const float* f_v  = (const float*)d_in[2];
  const float* r_qk = (const float*)d_in[3];
  const float* r_v  = (const float*)d_in[4];
  const float* f_kn = (const float*)d_in[5];
  const float* r_kn = (const float*)d_in[6];
  const float* nemb = (const float*)d_in[7];
  const float* W_all = (const float*)d_in[8];
  const float* b_all = (const float*)d_in[9];
  const float* W_fk  = (const float*)d_in[10];
  const float* b_fk  = (const float*)d_in[11];
  const float* W_rk  = (const float*)d_in[12];
  const float* b_rk  = (const float*)d_in[13];
  const float* W_o   = (const float*)d_in[14];
  const float* ln1s  = (const float*)d_in[15];
  const float* ln1b  = (const float*)d_in[16];
  const float* ln2s  = (const float*)d_in[17];
  const float* ln2b  = (const float*)d_in[18];

  float* ws = (float*)d_ws;
  size_t off = 0;
  auto alloc = [&](size_t nf) { float* p = ws + off; off += nf; return p; };
  float* nx      = alloc((size_t)BS * DMODEL);
  float* nx2     = alloc((size_t)BS * DMODEL);
  float* embn    = alloc(6 * NEXP * DSP);
  float* h_all   = alloc((size_t)BS * HALL_N);
  float* hk2     = alloc((size_t)2 * BS * DSP);    // h_fk2 | h_rk2 contiguous
  float* w8      = alloc((size_t)8 * BS * NEXP);
  float* x1      = alloc((size_t)BS * DMODEL);
  float* compactFf = alloc((size_t)3 * 2 * BS * RANK);    // 3 routes x 8192 x 512 u16
  float* compactRf = alloc((size_t)3 * 2 * BS * DMODEL);  // 3 routes x 8192 x 1024 u16 (+partials)
  int* lists   = (int*)(ws + off); off += (size_t)8 * NEXP * BS;
  int* slotmap = (int*)(ws + off); off += (size_t)8 * NEXP * BS;
  int* counts  = (int*)(ws + off); off += 8 * NEXP;
  int* offsb   = (int*)(ws + off); off += 8 * NEXP;
  u16* nxb  = (u16*)(ws + off); off += (size_t)BS * DMODEL / 2;
  u16* fqb  = (u16*)(ws + off); off += (size_t)3 * BS * RANK / 2;  // fqb|fkb|fvb contiguous
  u16* fnb  = (u16*)(ws + off); off += (size_t)BS * RANK / 2;
  u16* Qbb  = (u16*)(ws + off); off += (size_t)3 * BS * DMODEL / 2; // Q|K|V contiguous
  u16* attnOb = (u16*)(ws + off); off += (size_t)BS * DMODEL / 2;
  u16* woT  = (u16*)(ws + off); off += (size_t)DMODEL * DMODEL / 2;
  u16* wbufF = (u16*)(ws + off); off += (size_t)3 * NEXP * DMODEL * RANK / 2; // f_qk|f_v|f_kn
  u16* wbufR = (u16*)(ws + off); off += (size_t)3 * NEXP * RANK * DMODEL / 2; // r_qk|r_v|r_kn
  u16* compactF = (u16*)compactFf;
  u16* compactR = (u16*)compactRf;
  u16* fkb = fqb + (size_t)BS * RANK;
  u16* fvb = fkb + (size_t)BS * RANK;
  u16* Kbb = Qbb + (size_t)BS * DMODEL;
  u16* Vbb = Kbb + (size_t)BS * DMODEL;
  float* h_fk2 = hk2;
  float* partA = compactRf;  // W_all partials: 4*BS*384 = 3.1M fl < 12.6M
  float* partK = compactRf;  // W_fk+W_rk partials: 16*BS*64 = 2.1M fl
  (void)fkb; (void)fvb; (void)Kbb; (void)Vbb;

  // ---- weights & norms (no deps): single merged wconv for all 7 weight tensors ----
  embnorm_kernel<<<6 * NEXP, DSP, 0, stream>>>(nemb, embn);
  wconv_all_kernel<<<12416, 512, 0, stream>>>(f_qk, f_v, f_kn, r_qk, r_v, r_kn,
                                              W_o, wbufF, wbufR, woT);

  // ---- attention circuit ----
  ln_kernel<<<BS, 256, 0, stream>>>(x, ln1s, ln1b, nx, nxb);
  gemm_splitk<<<dim3(HALL_N / 64, BS / 64, 4), 256, 0, stream>>>(
      nx, W_all, partA, BS, HALL_N, DMODEL, DMODEL / 4);
  reduce_bias_kernel<<<(BS * HALL_N / 4 + 255) / 256, 256, 0, stream>>>(
      partA, b_all, h_all, BS * HALL_N, HALL_N, 4);

  route_kernel<<<dim3(BS, 6), 64, 0, stream>>>(h_all, DSP, HALL_N, embn, 0, w8);
  bucket_kernel<<<dim3(NEXP, 6), 64, 0, stream>>>(w8, lists, slotmap, counts, 0);
  scan32_kernel<<<6, 64, 0, stream>>>(counts, offsb);

  // merged feature GEMM: routes 0,1,2 (slots f_qk,f_qk,f_v)
  expert_gemm_mfma<<<dim3(RANK / 64, 3 * NEXP, BS / 128), 256, 0, stream>>>(
      nxb, wbufF, lists, counts, offsb, compactF,
      0, 0, 0, 1, 0, DMODEL, RANK);
  gather_combine<RANK, false><<<dim3(BS, 3), 256, 0, stream>>>(
      compactF, w8, slotmap, offsb, nullptr, nullptr, fqb);

  // merged restore GEMM: routes 3,4,5 (slots r_qk,r_qk,r_v), X = fqb|fkb|fvb
  expert_gemm_mfma<<<dim3(DMODEL / 64, 3 * NEXP, BS / 128), 256, 0, stream>>>(
      fqb, wbufR, lists, counts, offsb, compactR,
      3, 0, 0, 1, (size_t)BS * RANK, RANK, DMODEL);
  gather_combine<DMODEL, false><<<dim3(BS, 3), 256, 0, stream>>>(
      compactR, w8 + 3 * WSTR, slotmap + 3 * LSTR, offsb + 3 * NEXP,
      nullptr, nullptr, Qbb);

  attn_mfma<<<dim3(SEQ / 64, NHEAD, BATCH), 256, 0, stream>>>(Qbb, Kbb, Vbb, attnOb);

  dense_gemm_mfma<true><<<dim3(DMODEL / 64, BS / 64), 256, 0, stream>>>(
      attnOb, woT, x, x1, BS, DMODEL, DMODEL);

  // ---- knowledge circuit ----
  ln_kernel<<<BS, 256, 0, stream>>>(x1, ln2s, ln2b, nx2, nxb);
  gemm_splitk2<<<dim3(1, BS / 64, 16), 256, 0, stream>>>(
      nx2, W_fk, W_rk, partK, BS, DSP, DMODEL, DMODEL / 8);
  reduce_bias2_kernel<<<dim3((BS * DSP / 4 + 255) / 256, 2), 256, 0, stream>>>(
      partK, b_fk, b_rk, h_fk2, BS * DSP, DSP, 8);
  route_kernel<<<dim3(BS, 2), 64, 0, stream>>>(h_fk2, (size_t)BS * DSP, DSP, embn, 6, w8);
  bucket_kernel<<<dim3(NEXP, 2), 64, 0, stream>>>(w8, lists, slotmap, counts, 6);
  scan32_kernel<<<2, 64, 0, stream>>>(counts + 6 * NEXP, offsb + 6 * NEXP);

  expert_gemm_mfma<<<dim3(RANK / 64, NEXP, BS / 128), 256, 0, stream>>>(
      nxb, wbufF, lists, counts, offsb, compactF,
      6, 2, 2, 2, 0, DMODEL, RANK);
  gather_combine<RANK, false><<<dim3(BS, 1), 256, 0, stream>>>(
      compactF, w8 + 6 * WSTR, slotmap + 6 * LSTR, offsb + 6 * NEXP,
      nullptr, nullptr, fnb);
  expert_gemm_mfma<<<dim3(DMODEL / 64, NEXP, BS / 128), 256, 0, stream>>>(
      fnb, wbufR, lists, counts, offsb, compactR,
      7, 2, 2, 2, 0, RANK, DMODEL);
  // d_out = x1 + restore(featN)
  gather_combine<DMODEL, true><<<dim3(BS, 1), 256, 0, stream>>>(
      compactR, w8 + 7 * WSTR, slotmap + 7 * LSTR, offsb + 7 * NEXP,
      x1, (float*)d_out, nullptr);
}